// Round 6
// baseline (627.604 us; speedup 1.0000x reference)
//
#include <hip/hip_runtime.h>
#include <hip/hip_fp16.h>

// LSTM_48850958024796 — R6: un-fused input projection (parallel GEMM on full
// machine), K=128 scan, custom no-vmcnt-drain barrier, transposed layouts.
// Scan algorithm (R3-proven): gates^T = W(A) @ [h|x|1]^T(B), cols packed
// gate-interleaved (n'=4j+gate): lane(q,l16) tile mt owns all 4 gates of
// (m=l16, j=mt*4+q) in acc[0..3]; c state in VGPRs; 1 barrier/step.
// R6 keys:
//  - barrier_nv(): s_waitcnt lgkmcnt(0); s_barrier — does NOT drain vmcnt, so
//    per-step global prefetch loads / h stores stay in flight across barriers
//    (the compiler's vmcnt(0)-before-s_barrier was ~2000 cyc/step of stall)
//  - h0fT/h0bT [t][1024][100] bf16: per block-step store = 3200 B contiguous
//  - xgT [t*1024+b][400] fp16 gate-interleaved, staged via depth-2 register
//    pipeline into a double-buffered LDS ring (row stride 404 halves)

typedef __attribute__((ext_vector_type(8))) short bf16x8;
typedef __attribute__((ext_vector_type(4))) float f32x4;

constexpr int Bsz = 1024, Tt = 128, IN_ = 5, H = 100, G = 400, D1 = 200;
constexpr int NP = 512;   // packed gate cols (32 tiles of 16)
constexpr int NT = 25;    // real tiles (400/16)
constexpr int XGP = 404;  // xg LDS row stride (halves)

__device__ __forceinline__ float sigm(float x)   { return 1.f / (1.f + __expf(-x)); }
__device__ __forceinline__ float tanhf_(float x) { return 1.f - 2.f / (__expf(2.f * x) + 1.f); }
__device__ __forceinline__ unsigned short f2bf(float f) {
  unsigned u = __float_as_uint(f);
  u += 0x7fff + ((u >> 16) & 1);
  return (unsigned short)(u >> 16);
}
// workgroup barrier WITHOUT the compiler's vmcnt(0) drain (LDS-only wait)
__device__ __forceinline__ void barrier_nv() {
  asm volatile("s_waitcnt lgkmcnt(0)\n\ts_barrier" ::: "memory");
}

// packed col n' (0..511): j=n'>>2, gate=n'&3, src row n = gate*100+j; j>=100->0
// dst[(g*NP+n')*8+jj], k=g*8+jj: k<KA -> wA[n][k]; k==bias_k -> b1[n]+b2[n];
// KA<=... (x-part for l0 via wB at kbo); else 0.
__global__ void pack_aug(const float* __restrict__ wA, int KA,
                         const float* __restrict__ wB, int KB, int kbo,
                         const float* __restrict__ b1, const float* __restrict__ b2,
                         int bias_k, unsigned short* __restrict__ dst, int Kg) {
  int idx = blockIdx.x * 256 + threadIdx.x;
  if (idx >= Kg * NP * 8) return;
  int jj = idx & 7, rest = idx >> 3;
  int np_ = rest % NP, g = rest / NP;
  int j = np_ >> 2, gate = np_ & 3;
  int k = g * 8 + jj;
  float v = 0.f;
  if (j < H) {
    int n = gate * H + j;
    if (k < KA) v = wA[n * KA + k];
    else if (KB > 0 && k >= kbo && k < kbo + KB) v = wB[n * KB + (k - kbo)];
    else if (k == bias_k) v = b1[n] + b2[n];
  }
  dst[idx] = f2bf(v);
}

// x[b][t][5] f32 -> xT[t][b][5] bf16
__global__ void pack_x(const float* __restrict__ x, unsigned short* __restrict__ xT) {
  int idx = blockIdx.x * 256 + threadIdx.x;
  if (idx >= Bsz * Tt * IN_) return;
  int e = idx % IN_, bt = idx / IN_;
  int t = bt % Tt, b = bt / Tt;
  xT[((size_t)t * Bsz + b) * IN_ + e] = f2bf(x[idx]);
}

// ---------------- layer 0 scan (grid = 64 x 2 dirs, 512 thr) ----------------
__global__ __launch_bounds__(512, 2) void lstm_l0(
    const unsigned short* __restrict__ xT,
    const unsigned short* __restrict__ pk_f, const unsigned short* __restrict__ pk_b,
    unsigned short* __restrict__ h0fT, unsigned short* __restrict__ h0bT) {
  __shared__ __align__(16) short A_s[2][16][16][8];  // [buf][kg][m][jj], K=128

  const int tid = threadIdx.x;
  const int lane = tid & 63, w = tid >> 6;
  const int q = lane >> 4, l16 = lane & 15;
  const int b0 = blockIdx.x * 16;
  const int dir = blockIdx.y;
  const unsigned short* pk = dir ? pk_b : pk_f;
  unsigned short* hT = dir ? h0bT : h0fT;

  for (int i = tid; i < 2 * 16 * 16 * 8; i += 512) ((short*)A_s)[i] = 0;

  int mts[4]; bool tv[4];
  bf16x8 wfrag[4][4];
#pragma unroll
  for (int i = 0; i < 4; ++i) {
    int mt = w + 8 * i; mts[i] = mt; tv[i] = (mt < NT);
#pragma unroll
    for (int kt = 0; kt < 4; ++kt)
      wfrag[i][kt] = *(const bf16x8*)(pk + ((size_t)(kt * 4 + q) * NP + mt * 16 + l16) * 8);
  }
  float c[4] = {0.f, 0.f, 0.f, 0.f};
  const int xm = tid / IN_, xe = tid - xm * IN_;        // x loader (tid<80)
  const int sm = tid / 25, sj = (tid - (tid / 25) * 25) * 4;  // h store (tid<400)
  __syncthreads();
  if (tid < 16) {  // bias-one col k=105 (kg13,jj1), both bufs
    A_s[0][13][tid][1] = (short)f2bf(1.f);
    A_s[1][13][tid][1] = (short)f2bf(1.f);
  }
  if (tid < 80) {  // x(t_first) -> buf0
    int t0 = dir ? (Tt - 1) : 0;
    int k = 100 + xe;
    A_s[0][k >> 3][xm][k & 7] = (short)xT[((size_t)t0 * Bsz + b0 + xm) * IN_ + xe];
  }
  __syncthreads();

  int p = 0;
  for (int step = 0; step < Tt; ++step) {
    const int t = dir ? (Tt - 1 - step) : step;
    // coalesced store of h(prev) from buf p; never drained in-loop (barrier_nv)
    if (step > 0 && tid < 400) {
      int tp = dir ? (t + 1) : (t - 1);
      uint2 hv = *(const uint2*)&A_s[p][sj >> 3][sm][sj & 7];
      *(uint2*)(hT + ((size_t)tp * Bsz + b0 + sm) * H + sj) = hv;
    }
    unsigned short xn = 0;
    const bool do_x = (tid < 80) && (step < Tt - 1);
    if (do_x) {
      int tn = dir ? (t - 1) : (t + 1);
      xn = xT[((size_t)tn * Bsz + b0 + xm) * IN_ + xe];
    }
    bf16x8 hfrag[4];
#pragma unroll
    for (int kt = 0; kt < 4; ++kt) hfrag[kt] = *(const bf16x8*)A_s[p][kt * 4 + q][l16];
    f32x4 acc[4];
#pragma unroll
    for (int i = 0; i < 4; ++i) {
      if (!tv[i]) continue;
      acc[i] = (f32x4){0.f, 0.f, 0.f, 0.f};
#pragma unroll
      for (int kt = 0; kt < 4; ++kt)
        acc[i] = __builtin_amdgcn_mfma_f32_16x16x32_bf16(wfrag[i][kt], hfrag[kt], acc[i], 0, 0, 0);
    }
#pragma unroll
    for (int i = 0; i < 4; ++i) {
      if (!tv[i]) continue;
      const int j = mts[i] * 4 + q;
      float cc = sigm(acc[i][1]) * c[i] + sigm(acc[i][0]) * tanhf_(acc[i][2]);
      c[i] = cc;
      float h = sigm(acc[i][3]) * tanhf_(cc);
      A_s[1 - p][j >> 3][l16][j & 7] = (short)f2bf(h);
    }
    if (do_x) {
      int k = 100 + xe;
      A_s[1 - p][k >> 3][xm][k & 7] = (short)xn;
    }
    barrier_nv();
    p ^= 1;
  }
  if (tid < 400) {  // final h
    int tl = dir ? 0 : (Tt - 1);
    uint2 hv = *(const uint2*)&A_s[p][sj >> 3][sm][sj & 7];
    *(uint2*)(hT + ((size_t)tl * Bsz + b0 + sm) * H + sj) = hv;
  }
}

// ---- xgT[t*1024+b][400] = [h0f|h0b] @ W_ih_l1f^T + bias (fp16, interleaved) --
__global__ __launch_bounds__(256, 2) void gemm_xg(
    const unsigned short* __restrict__ h0fT, const unsigned short* __restrict__ h0bT,
    const unsigned short* __restrict__ pkw, __half* __restrict__ xg) {
  __shared__ __align__(16) short A_s[28][64][8];  // K=224 aug (k=200 bias-one)
  __shared__ __align__(16) short B_s[28][64][8];
  const int tid = threadIdx.x;
  const int lane = tid & 63, w = tid >> 6;
  const int q = lane >> 4, l16 = lane & 15;
  const int r0 = blockIdx.x * 64;           // rows r = t*1024+b; 16 blocks per t
  const size_t base = (size_t)r0 * H;       // h0xT flat offset of row block

  for (int i = tid; i < 3 * 64 * 8; i += 256) {  // kg 25..27: zero + bias-one
    int jj = i & 7, gl = i >> 9;
    ((short*)&A_s[25][0][0])[i] = (short)((gl == 0 && jj == 0) ? f2bf(1.f) : 0);
  }
  for (int r = 0; r < 7; ++r) {  // stage h0f (k=0..99) and h0b (k=100..199)
    int idx = tid + 256 * r;
    if (idx < 1600) {
      int m = idx / 25, j0 = (idx - (idx / 25) * 25) * 4;
      *(uint2*)&A_s[j0 >> 3][m][j0 & 7] = *(const uint2*)(h0fT + base + m * H + j0);
      int k = 100 + j0;
      *(uint2*)&A_s[k >> 3][m][k & 7] = *(const uint2*)(h0bT + base + m * H + j0);
    }
  }
  __syncthreads();

  for (int nb = 0; nb < 7; ++nb) {
    for (int cc = tid; cc < 28 * 64; cc += 256) {
      int g = cc >> 6, col = cc & 63;
      *(uint4*)B_s[g][col] = *(const uint4*)(pkw + ((size_t)g * NP + nb * 64 + col) * 8);
    }
    __syncthreads();
    f32x4 acc[4];
#pragma unroll
    for (int nt = 0; nt < 4; ++nt) acc[nt] = (f32x4){0.f, 0.f, 0.f, 0.f};
#pragma unroll
    for (int kt = 0; kt < 7; ++kt) {
      bf16x8 af = *(const bf16x8*)A_s[kt * 4 + q][w * 16 + l16];
#pragma unroll
      for (int nt = 0; nt < 4; ++nt) {
        bf16x8 bf = *(const bf16x8*)B_s[kt * 4 + q][nt * 16 + l16];
        acc[nt] = __builtin_amdgcn_mfma_f32_16x16x32_bf16(af, bf, acc[nt], 0, 0, 0);
      }
    }
#pragma unroll
    for (int nt = 0; nt < 4; ++nt) {
      int col = nb * 64 + nt * 16 + l16;
      if (col < G) {
#pragma unroll
        for (int r = 0; r < 4; ++r) {
          int row = r0 + w * 16 + q * 4 + r;
          xg[(size_t)row * G + col] = __float2half(acc[nt][r]);
        }
      }
    }
    __syncthreads();
  }
}

// ---- layer 1: fwd scan (K=128) + bwd single step + FC + softmax ------------
__global__ __launch_bounds__(512, 2) void lstm_l1(
    const unsigned short* __restrict__ h0fT, const unsigned short* __restrict__ h0bT,
    const unsigned short* __restrict__ pk_hh, const unsigned short* __restrict__ pk1b,
    const __half* __restrict__ xg,
    const float* __restrict__ fc_w, const float* __restrict__ fc_b,
    float* __restrict__ out) {
  __shared__ __align__(16) short A_s[2][16][16][8];      // h1, K=128
  __shared__ __align__(16) short A2_s[28][16][8];        // epilogue [h0|1] K=224
  __shared__ __align__(8) unsigned short xg_s[2][16 * XGP];
  __shared__ float hf_s[16][H];
  __shared__ float hb_s[16][H];
  __shared__ float fcw_s[3 * D1];
  __shared__ float fcb_s[3];
  __shared__ float logit_s[16][3];

  const int tid = threadIdx.x;
  const int lane = tid & 63, w = tid >> 6;
  const int q = lane >> 4, l16 = lane & 15;
  const int b0 = blockIdx.x * 16;
  const uint2* xg2 = (const uint2*)xg;  // 100 uint2 (=400 halves) per row

  for (int i = tid; i < 2 * 16 * 16 * 8; i += 512) ((short*)A_s)[i] = 0;
  for (int i = tid; i < 3 * 16 * 8; i += 512) {   // A2 kg25..27 zero + bias-one
    int jj = i & 7, gl = i >> 7;
    ((short*)&A2_s[25][0][0])[i] = (short)((gl == 0 && jj == 0) ? f2bf(1.f) : 0);
  }
  for (int i = tid; i < 3 * D1; i += 512) fcw_s[i] = fc_w[i];
  if (tid < 3) fcb_s[tid] = fc_b[tid];
  // stage xg(t=0) -> buf0
  for (int r = 0; r < 4; ++r) {
    int idx = tid + 512 * r;
    if (idx < 1600) {
      int m = idx / 100, cu = idx - (idx / 100) * 100;
      *(uint2*)&xg_s[0][m * XGP + cu * 4] = xg2[((size_t)b0 + m) * 100 + cu];
    }
  }

  int mts[4]; bool tv[4];
  bf16x8 wfrag[4][4];
#pragma unroll
  for (int i = 0; i < 4; ++i) {
    int mt = w + 8 * i; mts[i] = mt; tv[i] = (mt < NT);
#pragma unroll
    for (int kt = 0; kt < 4; ++kt)
      wfrag[i][kt] = *(const bf16x8*)(pk_hh + ((size_t)(kt * 4 + q) * NP + mt * 16 + l16) * 8);
  }
  float c[4] = {0.f, 0.f, 0.f, 0.f};
  // depth-2 xg prefetch pipeline: preA holds data for t+1
  int pm[4], pc[4]; bool pvld[4];
#pragma unroll
  for (int r = 0; r < 4; ++r) {
    int idx = tid + 512 * r;
    pvld[r] = (idx < 1600);
    pm[r] = idx / 100; pc[r] = idx - (idx / 100) * 100;
  }
  uint2 preA[4];
#pragma unroll
  for (int r = 0; r < 4; ++r)
    if (pvld[r]) preA[r] = xg2[((size_t)Bsz + b0 + pm[r]) * 100 + pc[r]];  // t=1
  __syncthreads();

  int p = 0;
  for (int t = 0; t < Tt; ++t) {
    uint2 preB[4];
    if (t < Tt - 2) {
#pragma unroll
      for (int r = 0; r < 4; ++r)
        if (pvld[r]) preB[r] = xg2[((size_t)(t + 2) * Bsz + b0 + pm[r]) * 100 + pc[r]];
    }
    bf16x8 hfrag[4];
#pragma unroll
    for (int kt = 0; kt < 4; ++kt) hfrag[kt] = *(const bf16x8*)A_s[p][kt * 4 + q][l16];
    f32x4 acc[4];
#pragma unroll
    for (int i = 0; i < 4; ++i) {
      if (!tv[i]) continue;
      acc[i] = (f32x4){0.f, 0.f, 0.f, 0.f};
#pragma unroll
      for (int kt = 0; kt < 4; ++kt)
        acc[i] = __builtin_amdgcn_mfma_f32_16x16x32_bf16(wfrag[i][kt], hfrag[kt], acc[i], 0, 0, 0);
    }
#pragma unroll
    for (int i = 0; i < 4; ++i) {
      if (!tv[i]) continue;
      const int j = mts[i] * 4 + q;
      uint2 gx = *(const uint2*)&xg_s[p][l16 * XGP + 4 * j];
      float2 f01 = __half22float2(*(const __half2*)&gx.x);
      float2 f23 = __half22float2(*(const __half2*)&gx.y);
      float gi = acc[i][0] + f01.x, gf = acc[i][1] + f01.y;
      float gg = acc[i][2] + f23.x, go = acc[i][3] + f23.y;
      float cc = sigm(gf) * c[i] + sigm(gi) * tanhf_(gg);
      c[i] = cc;
      float h = sigm(go) * tanhf_(cc);
      A_s[1 - p][j >> 3][l16][j & 7] = (short)f2bf(h);
      if (t == Tt - 1) hf_s[l16][j] = h;
    }
    if (t < Tt - 1) {  // drain preA (data for t+1) into the other buffer
#pragma unroll
      for (int r = 0; r < 4; ++r)
        if (pvld[r]) *(uint2*)&xg_s[1 - p][pm[r] * XGP + pc[r] * 4] = preA[r];
#pragma unroll
      for (int r = 0; r < 4; ++r) preA[r] = preB[r];
    }
    barrier_nv();
    p ^= 1;
  }

  // ---- layer-1 backward single step at t=T-1 (h=c=0) ----
  for (int r = 0; r < 1; ++r) {}  // (no-op)
  {
    const size_t base = ((size_t)(Tt - 1) * Bsz + b0) * H;
    for (int idx = tid; idx < 400; idx += 512) {
      int m = idx / 25, j0 = (idx - (idx / 25) * 25) * 4;
      *(uint2*)&A2_s[j0 >> 3][m][j0 & 7] = *(const uint2*)(h0fT + base + m * H + j0);
      int k = 100 + j0;
      *(uint2*)&A2_s[k >> 3][m][k & 7] = *(const uint2*)(h0bT + base + m * H + j0);
    }
  }
  __syncthreads();
  {
    f32x4 acc[4];
#pragma unroll
    for (int i = 0; i < 4; ++i) acc[i] = (f32x4){0.f, 0.f, 0.f, 0.f};
#pragma unroll
    for (int kt = 0; kt < 7; ++kt) {
      bf16x8 hf = *(const bf16x8*)A2_s[kt * 4 + q][l16];
#pragma unroll
      for (int i = 0; i < 4; ++i) {
        if (!tv[i]) continue;
        bf16x8 wf = *(const bf16x8*)(pk1b + ((size_t)(kt * 4 + q) * NP + mts[i] * 16 + l16) * 8);
        acc[i] = __builtin_amdgcn_mfma_f32_16x16x32_bf16(wf, hf, acc[i], 0, 0, 0);
      }
    }
#pragma unroll
    for (int i = 0; i < 4; ++i) {
      if (!tv[i]) continue;
      const int j = mts[i] * 4 + q;
      float cc = sigm(acc[i][0]) * tanhf_(acc[i][2]);   // c_prev = 0
      hb_s[l16][j] = sigm(acc[i][3]) * tanhf_(cc);
    }
  }
  __syncthreads();

  // ---- FC (3x200) + softmax ----
  if (tid < 48) {
    int m = tid / 3, cls = tid - m * 3;
    float s = fcb_s[cls];
    for (int j = 0; j < H; ++j) s += fcw_s[cls * D1 + j] * hf_s[m][j];
    for (int j = 0; j < H; ++j) s += fcw_s[cls * D1 + H + j] * hb_s[m][j];
    logit_s[m][cls] = s;
  }
  __syncthreads();
  if (tid < 16) {
    float a = logit_s[tid][0], b = logit_s[tid][1], cc = logit_s[tid][2];
    float mx = fmaxf(a, fmaxf(b, cc));
    float e0 = __expf(a - mx), e1 = __expf(b - mx), e2 = __expf(cc - mx);
    float inv = 1.f / (e0 + e1 + e2);
    out[(b0 + tid) * 3 + 0] = e0 * inv;
    out[(b0 + tid) * 3 + 1] = e1 * inv;
    out[(b0 + tid) * 3 + 2] = e2 * inv;
  }
}

extern "C" void kernel_launch(void* const* d_in, const int* in_sizes, int n_in,
                              void* d_out, int out_size, void* d_ws, size_t ws_size,
                              hipStream_t stream) {
  const float* x        = (const float*)d_in[0];
  const float* w_ih_l0f = (const float*)d_in[1];
  const float* w_hh_l0f = (const float*)d_in[2];
  const float* b_ih_l0f = (const float*)d_in[3];
  const float* b_hh_l0f = (const float*)d_in[4];
  const float* w_ih_l0b = (const float*)d_in[5];
  const float* w_hh_l0b = (const float*)d_in[6];
  const float* b_ih_l0b = (const float*)d_in[7];
  const float* b_hh_l0b = (const float*)d_in[8];
  const float* w_ih_l1f = (const float*)d_in[9];
  const float* w_hh_l1f = (const float*)d_in[10];
  const float* b_ih_l1f = (const float*)d_in[11];
  const float* b_hh_l1f = (const float*)d_in[12];
  const float* w_ih_l1b = (const float*)d_in[13];
  // d_in[14] = w_hh_l1b unused (reverse dir at t=T-1 has h=0)
  const float* b_ih_l1b = (const float*)d_in[15];
  const float* b_hh_l1b = (const float*)d_in[16];
  const float* fc_w     = (const float*)d_in[17];
  const float* fc_b     = (const float*)d_in[18];

  // ws: h0fT 13.1M | h0bT 13.1M | xgT 52.4M halves | xT | packs
  unsigned short* h0fT = (unsigned short*)d_ws;
  unsigned short* h0bT = h0fT + (size_t)Tt * Bsz * H;
  __half* xgT          = (__half*)(h0bT + (size_t)Tt * Bsz * H);
  unsigned short* xT   = (unsigned short*)(xgT + (size_t)Tt * Bsz * G);
  unsigned short* pk0f = xT + (size_t)Tt * Bsz * IN_;
  unsigned short* pk0b = pk0f + 16 * NP * 8;
  unsigned short* pkhh = pk0b + 16 * NP * 8;
  unsigned short* pkxg = pkhh + 16 * NP * 8;
  unsigned short* pk1b = pkxg + 28 * NP * 8;

  const int P16 = (16 * NP * 8 + 255) / 256, P28 = (28 * NP * 8 + 255) / 256;
  pack_aug<<<P16, 256, 0, stream>>>(w_hh_l0f, 100, w_ih_l0f, 5, 100,
                                    b_ih_l0f, b_hh_l0f, 105, pk0f, 16);
  pack_aug<<<P16, 256, 0, stream>>>(w_hh_l0b, 100, w_ih_l0b, 5, 100,
                                    b_ih_l0b, b_hh_l0b, 105, pk0b, 16);
  pack_aug<<<P16, 256, 0, stream>>>(w_hh_l1f, 100, nullptr, 0, 0,
                                    b_ih_l1f, b_hh_l1f, -1, pkhh, 16);
  pack_aug<<<P28, 256, 0, stream>>>(w_ih_l1f, 200, nullptr, 0, 0,
                                    b_ih_l1f, b_hh_l1f, 200, pkxg, 28);
  pack_aug<<<P28, 256, 0, stream>>>(w_ih_l1b, 200, nullptr, 0, 0,
                                    b_ih_l1b, b_hh_l1b, 200, pk1b, 28);
  pack_x<<<(Bsz * Tt * IN_ + 255) / 256, 256, 0, stream>>>(x, xT);

  lstm_l0<<<dim3(Bsz / 16, 2), 512, 0, stream>>>(xT, pk0f, pk0b, h0fT, h0bT);
  gemm_xg<<<(Bsz * Tt) / 64, 256, 0, stream>>>(h0fT, h0bT, pkxg, xgT);
  lstm_l1<<<Bsz / 16, 512, 0, stream>>>(h0fT, h0bT, pkhh, pk1b, xgT,
                                        fc_w, fc_b, (float*)d_out);
}

// Round 7
// 567.403 us; speedup vs baseline: 1.1061x; 1.1061x over previous
//
#include <hip/hip_runtime.h>
#include <hip/hip_fp16.h>

// LSTM_48850958024796 — R7: 1024-thread scan blocks (16 waves = 4 waves/SIMD)
// for latency overlap; 2 gate-tiles/wave. Scan algorithm (R3-proven):
// gates^T = W(A) @ [h|x|1]^T(B), cols gate-interleaved (n'=4j+gate): lane
// (q,l16) of tile mt owns all 4 gates of (m=l16, j=mt*4+q) in acc[0..3];
// c state in VGPRs; one __syncthreads per step.
// Evidence R6: on-active-CU VALUBusy ~62% -> scans are VALU/latency bound at
// 2 waves/SIMD; work/CU is fixed (grid=64 batch tiles), so go 4 waves/SIMD.

typedef __attribute__((ext_vector_type(8))) short bf16x8;
typedef __attribute__((ext_vector_type(4))) float f32x4;

constexpr int Bsz = 1024, Tt = 128, IN_ = 5, H = 100, G = 400, D1 = 200;
constexpr int NP = 512;   // packed gate cols (32 tiles of 16)
constexpr int NT = 25;    // real tiles (400/16)
constexpr int XGP = 404;  // xg LDS row stride (halves)

__device__ __forceinline__ float sigm(float x)   { return 1.f / (1.f + __expf(-x)); }
__device__ __forceinline__ float tanhf_(float x) { return 1.f - 2.f / (__expf(2.f * x) + 1.f); }
__device__ __forceinline__ unsigned short f2bf(float f) {
  unsigned u = __float_as_uint(f);
  u += 0x7fff + ((u >> 16) & 1);
  return (unsigned short)(u >> 16);
}

// packed col n' (0..511): j=n'>>2, gate=n'&3, src row n = gate*100+j; j>=100->0
__global__ void pack_aug(const float* __restrict__ wA, int KA,
                         const float* __restrict__ wB, int KB, int kbo,
                         const float* __restrict__ b1, const float* __restrict__ b2,
                         int bias_k, unsigned short* __restrict__ dst, int Kg) {
  int idx = blockIdx.x * 256 + threadIdx.x;
  if (idx >= Kg * NP * 8) return;
  int jj = idx & 7, rest = idx >> 3;
  int np_ = rest % NP, g = rest / NP;
  int j = np_ >> 2, gate = np_ & 3;
  int k = g * 8 + jj;
  float v = 0.f;
  if (j < H) {
    int n = gate * H + j;
    if (k < KA) v = wA[n * KA + k];
    else if (KB > 0 && k >= kbo && k < kbo + KB) v = wB[n * KB + (k - kbo)];
    else if (k == bias_k) v = b1[n] + b2[n];
  }
  dst[idx] = f2bf(v);
}

// x[b][t][5] f32 -> xT[t][b][5] bf16
__global__ void pack_x(const float* __restrict__ x, unsigned short* __restrict__ xT) {
  int idx = blockIdx.x * 256 + threadIdx.x;
  if (idx >= Bsz * Tt * IN_) return;
  int e = idx % IN_, bt = idx / IN_;
  int t = bt % Tt, b = bt / Tt;
  xT[((size_t)t * Bsz + b) * IN_ + e] = f2bf(x[idx]);
}

// ------------- layer 0 scan (grid = 64 x 2 dirs, 1024 thr) ------------------
__global__ __launch_bounds__(1024, 1) void lstm_l0(
    const unsigned short* __restrict__ xT,
    const unsigned short* __restrict__ pk_f, const unsigned short* __restrict__ pk_b,
    unsigned short* __restrict__ h0fT, unsigned short* __restrict__ h0bT) {
  __shared__ __align__(16) short A_s[2][16][16][8];  // [buf][kg][m][jj], K=128

  const int tid = threadIdx.x;
  const int lane = tid & 63, w = tid >> 6;       // 16 waves
  const int q = lane >> 4, l16 = lane & 15;
  const int b0 = blockIdx.x * 16;
  const int dir = blockIdx.y;
  const unsigned short* pk = dir ? pk_b : pk_f;
  unsigned short* hT = dir ? h0bT : h0fT;

  for (int i = tid; i < 2 * 16 * 16 * 8; i += 1024) ((short*)A_s)[i] = 0;

  int mts[2]; bool tv[2];
  bf16x8 wfrag[2][4];
#pragma unroll
  for (int i = 0; i < 2; ++i) {
    int mt = w + 16 * i; mts[i] = mt; tv[i] = (mt < NT);
#pragma unroll
    for (int kt = 0; kt < 4; ++kt)
      wfrag[i][kt] = *(const bf16x8*)(pk + ((size_t)(kt * 4 + q) * NP + mt * 16 + l16) * 8);
  }
  float c[2] = {0.f, 0.f};
  const int xm = tid / IN_, xe = tid - xm * IN_;              // x loader (tid<80)
  const int sm = tid / 25, sj = (tid - (tid / 25) * 25) * 4;  // h store (tid<400)
  __syncthreads();
  if (tid < 16) {  // bias-one col k=105 (kg13,jj1), both bufs
    A_s[0][13][tid][1] = (short)f2bf(1.f);
    A_s[1][13][tid][1] = (short)f2bf(1.f);
  }
  if (tid < 80) {  // x(t_first) -> buf0
    int t0 = dir ? (Tt - 1) : 0;
    int k = 100 + xe;
    A_s[0][k >> 3][xm][k & 7] = (short)xT[((size_t)t0 * Bsz + b0 + xm) * IN_ + xe];
  }
  __syncthreads();

  int p = 0;
  for (int step = 0; step < Tt; ++step) {
    const int t = dir ? (Tt - 1 - step) : step;
    // coalesced store of h(prev) from buf p (16 x 200 B contiguous chunks)
    if (step > 0 && tid < 400) {
      int tp = dir ? (t + 1) : (t - 1);
      uint2 hv = *(const uint2*)&A_s[p][sj >> 3][sm][sj & 7];
      *(uint2*)(hT + ((size_t)tp * Bsz + b0 + sm) * H + sj) = hv;
    }
    unsigned short xn = 0;
    const bool do_x = (tid < 80) && (step < Tt - 1);
    if (do_x) {
      int tn = dir ? (t - 1) : (t + 1);
      xn = xT[((size_t)tn * Bsz + b0 + xm) * IN_ + xe];
    }
    bf16x8 hfrag[4];
#pragma unroll
    for (int kt = 0; kt < 4; ++kt) hfrag[kt] = *(const bf16x8*)A_s[p][kt * 4 + q][l16];
    f32x4 acc[2];
#pragma unroll
    for (int i = 0; i < 2; ++i) {
      if (!tv[i]) continue;
      acc[i] = (f32x4){0.f, 0.f, 0.f, 0.f};
#pragma unroll
      for (int kt = 0; kt < 4; ++kt)
        acc[i] = __builtin_amdgcn_mfma_f32_16x16x32_bf16(wfrag[i][kt], hfrag[kt], acc[i], 0, 0, 0);
    }
#pragma unroll
    for (int i = 0; i < 2; ++i) {
      if (!tv[i]) continue;
      const int j = mts[i] * 4 + q;
      float cc = sigm(acc[i][1]) * c[i] + sigm(acc[i][0]) * tanhf_(acc[i][2]);
      c[i] = cc;
      float h = sigm(acc[i][3]) * tanhf_(cc);
      A_s[1 - p][j >> 3][l16][j & 7] = (short)f2bf(h);
    }
    if (do_x) {
      int k = 100 + xe;
      A_s[1 - p][k >> 3][xm][k & 7] = (short)xn;
    }
    __syncthreads();
    p ^= 1;
  }
  if (tid < 400) {  // final h
    int tl = dir ? 0 : (Tt - 1);
    uint2 hv = *(const uint2*)&A_s[p][sj >> 3][sm][sj & 7];
    *(uint2*)(hT + ((size_t)tl * Bsz + b0 + sm) * H + sj) = hv;
  }
}

// ---- xgT[t*1024+b][400] = [h0f|h0b] @ W_ih_l1f^T + bias (fp16, interleaved) --
__global__ __launch_bounds__(256, 2) void gemm_xg(
    const unsigned short* __restrict__ h0fT, const unsigned short* __restrict__ h0bT,
    const unsigned short* __restrict__ pkw, __half* __restrict__ xg) {
  __shared__ __align__(16) short A_s[28][64][8];  // K=224 aug (k=200 bias-one)
  __shared__ __align__(16) short B_s[28][64][8];
  const int tid = threadIdx.x;
  const int lane = tid & 63, w = tid >> 6;
  const int q = lane >> 4, l16 = lane & 15;
  const int r0 = blockIdx.x * 64;          // rows r = t*1024+b
  const size_t base = (size_t)r0 * H;

  for (int i = tid; i < 3 * 64 * 8; i += 256) {  // kg 25..27: zero + bias-one
    int jj = i & 7, gl = i >> 9;
    ((short*)&A_s[25][0][0])[i] = (short)((gl == 0 && jj == 0) ? f2bf(1.f) : 0);
  }
  for (int r = 0; r < 7; ++r) {  // stage h0f (k=0..99) and h0b (k=100..199)
    int idx = tid + 256 * r;
    if (idx < 1600) {
      int m = idx / 25, j0 = (idx - (idx / 25) * 25) * 4;
      *(uint2*)&A_s[j0 >> 3][m][j0 & 7] = *(const uint2*)(h0fT + base + m * H + j0);
      int k = 100 + j0;
      *(uint2*)&A_s[k >> 3][m][k & 7] = *(const uint2*)(h0bT + base + m * H + j0);
    }
  }
  __syncthreads();

  for (int nb = 0; nb < 7; ++nb) {
    for (int cc = tid; cc < 28 * 64; cc += 256) {
      int g = cc >> 6, col = cc & 63;
      *(uint4*)B_s[g][col] = *(const uint4*)(pkw + ((size_t)g * NP + nb * 64 + col) * 8);
    }
    __syncthreads();
    f32x4 acc[4];
#pragma unroll
    for (int nt = 0; nt < 4; ++nt) acc[nt] = (f32x4){0.f, 0.f, 0.f, 0.f};
#pragma unroll
    for (int kt = 0; kt < 7; ++kt) {
      bf16x8 af = *(const bf16x8*)A_s[kt * 4 + q][w * 16 + l16];
#pragma unroll
      for (int nt = 0; nt < 4; ++nt) {
        bf16x8 bf = *(const bf16x8*)B_s[kt * 4 + q][nt * 16 + l16];
        acc[nt] = __builtin_amdgcn_mfma_f32_16x16x32_bf16(af, bf, acc[nt], 0, 0, 0);
      }
    }
#pragma unroll
    for (int nt = 0; nt < 4; ++nt) {
      int col = nb * 64 + nt * 16 + l16;
      if (col < G) {
#pragma unroll
        for (int r = 0; r < 4; ++r) {
          int row = r0 + w * 16 + q * 4 + r;
          xg[(size_t)row * G + col] = __float2half(acc[nt][r]);
        }
      }
    }
    __syncthreads();
  }
}

// ---- layer 1: fwd scan (K=128) + bwd single step + FC + softmax (1024 thr) --
__global__ __launch_bounds__(1024, 1) void lstm_l1(
    const unsigned short* __restrict__ h0fT, const unsigned short* __restrict__ h0bT,
    const unsigned short* __restrict__ pk_hh, const unsigned short* __restrict__ pk1b,
    const __half* __restrict__ xg,
    const float* __restrict__ fc_w, const float* __restrict__ fc_b,
    float* __restrict__ out) {
  __shared__ __align__(16) short A_s[2][16][16][8];      // h1, K=128
  __shared__ __align__(16) short A2_s[28][16][8];        // epilogue [h0|1] K=224
  __shared__ __align__(8) unsigned short xg_s[2][16 * XGP];
  __shared__ float hf_s[16][H];
  __shared__ float hb_s[16][H];
  __shared__ float fcw_s[3 * D1];
  __shared__ float fcb_s[3];
  __shared__ float logit_s[16][3];

  const int tid = threadIdx.x;
  const int lane = tid & 63, w = tid >> 6;   // 16 waves
  const int q = lane >> 4, l16 = lane & 15;
  const int b0 = blockIdx.x * 16;
  const uint2* xg2 = (const uint2*)xg;       // 100 uint2 per row

  for (int i = tid; i < 2 * 16 * 16 * 8; i += 1024) ((short*)A_s)[i] = 0;
  for (int i = tid; i < 3 * 16 * 8; i += 1024) {  // A2 kg25..27 zero + bias-one
    int jj = i & 7, gl = i >> 7;
    ((short*)&A2_s[25][0][0])[i] = (short)((gl == 0 && jj == 0) ? f2bf(1.f) : 0);
  }
  for (int i = tid; i < 3 * D1; i += 1024) fcw_s[i] = fc_w[i];
  if (tid < 3) fcb_s[tid] = fc_b[tid];
  // stage xg(t=0) -> buf0
  for (int r = 0; r < 2; ++r) {
    int idx = tid + 1024 * r;
    if (idx < 1600) {
      int m = idx / 100, cu = idx - (idx / 100) * 100;
      *(uint2*)&xg_s[0][m * XGP + cu * 4] = xg2[((size_t)b0 + m) * 100 + cu];
    }
  }

  int mts[2]; bool tv[2];
  bf16x8 wfrag[2][4];
#pragma unroll
  for (int i = 0; i < 2; ++i) {
    int mt = w + 16 * i; mts[i] = mt; tv[i] = (mt < NT);
#pragma unroll
    for (int kt = 0; kt < 4; ++kt)
      wfrag[i][kt] = *(const bf16x8*)(pk_hh + ((size_t)(kt * 4 + q) * NP + mt * 16 + l16) * 8);
  }
  float c[2] = {0.f, 0.f};
  // depth-2 xg prefetch pipeline (preA holds t+1)
  int pm[2], pc[2]; bool pvld[2];
#pragma unroll
  for (int r = 0; r < 2; ++r) {
    int idx = tid + 1024 * r;
    pvld[r] = (idx < 1600);
    pm[r] = idx / 100; pc[r] = idx - (idx / 100) * 100;
  }
  uint2 preA[2];
#pragma unroll
  for (int r = 0; r < 2; ++r)
    if (pvld[r]) preA[r] = xg2[((size_t)Bsz + b0 + pm[r]) * 100 + pc[r]];  // t=1
  __syncthreads();

  int p = 0;
  for (int t = 0; t < Tt; ++t) {
    uint2 preB[2];
    if (t < Tt - 2) {
#pragma unroll
      for (int r = 0; r < 2; ++r)
        if (pvld[r]) preB[r] = xg2[((size_t)(t + 2) * Bsz + b0 + pm[r]) * 100 + pc[r]];
    }
    bf16x8 hfrag[4];
#pragma unroll
    for (int kt = 0; kt < 4; ++kt) hfrag[kt] = *(const bf16x8*)A_s[p][kt * 4 + q][l16];
    f32x4 acc[2];
#pragma unroll
    for (int i = 0; i < 2; ++i) {
      if (!tv[i]) continue;
      acc[i] = (f32x4){0.f, 0.f, 0.f, 0.f};
#pragma unroll
      for (int kt = 0; kt < 4; ++kt)
        acc[i] = __builtin_amdgcn_mfma_f32_16x16x32_bf16(wfrag[i][kt], hfrag[kt], acc[i], 0, 0, 0);
    }
#pragma unroll
    for (int i = 0; i < 2; ++i) {
      if (!tv[i]) continue;
      const int j = mts[i] * 4 + q;
      uint2 gx = *(const uint2*)&xg_s[p][l16 * XGP + 4 * j];
      float2 f01 = __half22float2(*(const __half2*)&gx.x);
      float2 f23 = __half22float2(*(const __half2*)&gx.y);
      float gi = acc[i][0] + f01.x, gf = acc[i][1] + f01.y;
      float gg = acc[i][2] + f23.x, go = acc[i][3] + f23.y;
      float cc = sigm(gf) * c[i] + sigm(gi) * tanhf_(gg);
      c[i] = cc;
      float h = sigm(go) * tanhf_(cc);
      A_s[1 - p][j >> 3][l16][j & 7] = (short)f2bf(h);
      if (t == Tt - 1) hf_s[l16][j] = h;
    }
    if (t < Tt - 1) {  // drain preA (t+1 data) into the other buffer
#pragma unroll
      for (int r = 0; r < 2; ++r)
        if (pvld[r]) *(uint2*)&xg_s[1 - p][pm[r] * XGP + pc[r] * 4] = preA[r];
#pragma unroll
      for (int r = 0; r < 2; ++r) preA[r] = preB[r];
    }
    __syncthreads();
    p ^= 1;
  }

  // ---- layer-1 backward single step at t=T-1 (h=c=0) ----
  {
    const size_t base = ((size_t)(Tt - 1) * Bsz + b0) * H;
    if (tid < 400) {
      int m = tid / 25, j0 = (tid - (tid / 25) * 25) * 4;
      *(uint2*)&A2_s[j0 >> 3][m][j0 & 7] = *(const uint2*)(h0fT + base + m * H + j0);
      int k = 100 + j0;
      *(uint2*)&A2_s[k >> 3][m][k & 7] = *(const uint2*)(h0bT + base + m * H + j0);
    }
  }
  __syncthreads();
  {
    f32x4 acc[2];
#pragma unroll
    for (int i = 0; i < 2; ++i) acc[i] = (f32x4){0.f, 0.f, 0.f, 0.f};
#pragma unroll
    for (int kt = 0; kt < 7; ++kt) {
      bf16x8 hf = *(const bf16x8*)A2_s[kt * 4 + q][l16];
#pragma unroll
      for (int i = 0; i < 2; ++i) {
        if (!tv[i]) continue;
        bf16x8 wf = *(const bf16x8*)(pk1b + ((size_t)(kt * 4 + q) * NP + mts[i] * 16 + l16) * 8);
        acc[i] = __builtin_amdgcn_mfma_f32_16x16x32_bf16(wf, hf, acc[i], 0, 0, 0);
      }
    }
#pragma unroll
    for (int i = 0; i < 2; ++i) {
      if (!tv[i]) continue;
      const int j = mts[i] * 4 + q;
      float cc = sigm(acc[i][0]) * tanhf_(acc[i][2]);   // c_prev = 0
      hb_s[l16][j] = sigm(acc[i][3]) * tanhf_(cc);
    }
  }
  __syncthreads();

  // ---- FC (3x200) + softmax ----
  if (tid < 48) {
    int m = tid / 3, cls = tid - m * 3;
    float s = fcb_s[cls];
    for (int j = 0; j < H; ++j) s += fcw_s[cls * D1 + j] * hf_s[m][j];
    for (int j = 0; j < H; ++j) s += fcw_s[cls * D1 + H + j] * hb_s[m][j];
    logit_s[m][cls] = s;
  }
  __syncthreads();
  if (tid < 16) {
    float a = logit_s[tid][0], b = logit_s[tid][1], cc = logit_s[tid][2];
    float mx = fmaxf(a, fmaxf(b, cc));
    float e0 = __expf(a - mx), e1 = __expf(b - mx), e2 = __expf(cc - mx);
    float inv = 1.f / (e0 + e1 + e2);
    out[(b0 + tid) * 3 + 0] = e0 * inv;
    out[(b0 + tid) * 3 + 1] = e1 * inv;
    out[(b0 + tid) * 3 + 2] = e2 * inv;
  }
}

extern "C" void kernel_launch(void* const* d_in, const int* in_sizes, int n_in,
                              void* d_out, int out_size, void* d_ws, size_t ws_size,
                              hipStream_t stream) {
  const float* x        = (const float*)d_in[0];
  const float* w_ih_l0f = (const float*)d_in[1];
  const float* w_hh_l0f = (const float*)d_in[2];
  const float* b_ih_l0f = (const float*)d_in[3];
  const float* b_hh_l0f = (const float*)d_in[4];
  const float* w_ih_l0b = (const float*)d_in[5];
  const float* w_hh_l0b = (const float*)d_in[6];
  const float* b_ih_l0b = (const float*)d_in[7];
  const float* b_hh_l0b = (const float*)d_in[8];
  const float* w_ih_l1f = (const float*)d_in[9];
  const float* w_hh_l1f = (const float*)d_in[10];
  const float* b_ih_l1f = (const float*)d_in[11];
  const float* b_hh_l1f = (const float*)d_in[12];
  const float* w_ih_l1b = (const float*)d_in[13];
  // d_in[14] = w_hh_l1b unused (reverse dir at t=T-1 has h=0)
  const float* b_ih_l1b = (const float*)d_in[15];
  const float* b_hh_l1b = (const float*)d_in[16];
  const float* fc_w     = (const float*)d_in[17];
  const float* fc_b     = (const float*)d_in[18];

  unsigned short* h0fT = (unsigned short*)d_ws;
  unsigned short* h0bT = h0fT + (size_t)Tt * Bsz * H;
  __half* xgT          = (__half*)(h0bT + (size_t)Tt * Bsz * H);
  unsigned short* xT   = (unsigned short*)(xgT + (size_t)Tt * Bsz * G);
  unsigned short* pk0f = xT + (size_t)Tt * Bsz * IN_;
  unsigned short* pk0b = pk0f + 16 * NP * 8;
  unsigned short* pkhh = pk0b + 16 * NP * 8;
  unsigned short* pkxg = pkhh + 16 * NP * 8;
  unsigned short* pk1b = pkxg + 28 * NP * 8;

  const int P16 = (16 * NP * 8 + 255) / 256, P28 = (28 * NP * 8 + 255) / 256;
  pack_aug<<<P16, 256, 0, stream>>>(w_hh_l0f, 100, w_ih_l0f, 5, 100,
                                    b_ih_l0f, b_hh_l0f, 105, pk0f, 16);
  pack_aug<<<P16, 256, 0, stream>>>(w_hh_l0b, 100, w_ih_l0b, 5, 100,
                                    b_ih_l0b, b_hh_l0b, 105, pk0b, 16);
  pack_aug<<<P16, 256, 0, stream>>>(w_hh_l1f, 100, nullptr, 0, 0,
                                    b_ih_l1f, b_hh_l1f, -1, pkhh, 16);
  pack_aug<<<P28, 256, 0, stream>>>(w_ih_l1f, 200, nullptr, 0, 0,
                                    b_ih_l1f, b_hh_l1f, 200, pkxg, 28);
  pack_aug<<<P28, 256, 0, stream>>>(w_ih_l1b, 200, nullptr, 0, 0,
                                    b_ih_l1b, b_hh_l1b, 200, pk1b, 28);
  pack_x<<<(Bsz * Tt * IN_ + 255) / 256, 256, 0, stream>>>(x, xT);

  lstm_l0<<<dim3(Bsz / 16, 2), 1024, 0, stream>>>(xT, pk0f, pk0b, h0fT, h0bT);
  gemm_xg<<<(Bsz * Tt) / 64, 256, 0, stream>>>(h0fT, h0bT, pkxg, xgT);
  lstm_l1<<<Bsz / 16, 1024, 0, stream>>>(h0fT, h0bT, pkhh, pk1b, xgT,
                                         fc_w, fc_b, (float*)d_out);
}

// Round 9
// 450.659 us; speedup vs baseline: 1.3926x; 1.2591x over previous
//
#include <hip/hip_runtime.h>
#include <hip/hip_fp16.h>

// LSTM_48850958024796 — R9: R8's 8-row spread with exec-safe cross-lane ops.
// Scan math (R3-proven): gates^T = W(A) @ [h|x|1]^T(B), cols gate-interleaved
// (n'=4j+gate). With 8 batch rows/block, tile mt's gates live in lanes l16<8.
// Upper lanes (l16>=8) take the SECOND tile's gates from lane&~8 via
// ds_swizzle(0x17) — executed UNCONDITIONALLY by all lanes (R8's divergent
// __shfl ternary risked undefined reads from inactive lanes). Each lane runs
// the cell update for exactly one (m,j): half R7's VALU issue, 2x the CUs.

typedef __attribute__((ext_vector_type(8))) short bf16x8;
typedef __attribute__((ext_vector_type(4))) float f32x4;

constexpr int Bsz = 1024, Tt = 128, IN_ = 5, H = 100, G = 400, D1 = 200;
constexpr int NP = 512;   // packed gate cols (32 tiles of 16)
constexpr int NT = 25;    // real tiles (400/16)
constexpr int MB = 8;     // batch rows per block
constexpr int XGP = 404;  // xg LDS row stride (halves)

__device__ __forceinline__ float sigm(float x)   { return 1.f / (1.f + __expf(-x)); }
__device__ __forceinline__ float tanhf_(float x) { return 1.f - 2.f / (__expf(2.f * x) + 1.f); }
__device__ __forceinline__ unsigned short f2bf(float f) {
  unsigned u = __float_as_uint(f);
  u += 0x7fff + ((u >> 16) & 1);
  return (unsigned short)(u >> 16);
}
// every lane receives the value held by lane (lane & ~8); unconditional.
__device__ __forceinline__ float partner8(float v) {
  return __uint_as_float(
      (unsigned)__builtin_amdgcn_ds_swizzle((int)__float_as_uint(v), 0x17));
}

// packed col n' (0..511): j=n'>>2, gate=n'&3, src row n = gate*100+j; j>=100->0
__device__ __forceinline__ void pack_body(
    const float* wA, int KA, const float* wB, int KB, int kbo,
    const float* b1, const float* b2, int bias_k,
    unsigned short* dst, int Kg, int idx) {
  if (idx >= Kg * NP * 8) return;
  int jj = idx & 7, rest = idx >> 3;
  int np_ = rest % NP, g = rest / NP;
  int j = np_ >> 2, gate = np_ & 3;
  int k = g * 8 + jj;
  float v = 0.f;
  if (j < H) {
    int n = gate * H + j;
    if (k < KA) v = wA[n * KA + k];
    else if (KB > 0 && k >= kbo && k < kbo + KB) v = wB[n * KB + (k - kbo)];
    else if (k == bias_k) v = b1[n] + b2[n];
  }
  dst[idx] = f2bf(v);
}

__global__ void pack_all(
    const float* __restrict__ w_hh_l0f, const float* __restrict__ w_ih_l0f,
    const float* __restrict__ b_ih_l0f, const float* __restrict__ b_hh_l0f,
    const float* __restrict__ w_hh_l0b, const float* __restrict__ w_ih_l0b,
    const float* __restrict__ b_ih_l0b, const float* __restrict__ b_hh_l0b,
    const float* __restrict__ w_hh_l1f, const float* __restrict__ b_ih_l1f,
    const float* __restrict__ b_hh_l1f,
    const float* __restrict__ w_ih_l1f, const float* __restrict__ w_ih_l1b,
    const float* __restrict__ b_ih_l1b, const float* __restrict__ b_hh_l1b,
    const float* __restrict__ x,
    unsigned short* __restrict__ pk0f, unsigned short* __restrict__ pk0b,
    unsigned short* __restrict__ pkhh, unsigned short* __restrict__ pkxg,
    unsigned short* __restrict__ pk1b, unsigned short* __restrict__ xT) {
  int idx = blockIdx.x * 256 + threadIdx.x;
  switch (blockIdx.y) {
    case 0: pack_body(w_hh_l0f, 100, w_ih_l0f, 5, 100, b_ih_l0f, b_hh_l0f, 105, pk0f, 16, idx); break;
    case 1: pack_body(w_hh_l0b, 100, w_ih_l0b, 5, 100, b_ih_l0b, b_hh_l0b, 105, pk0b, 16, idx); break;
    case 2: pack_body(w_hh_l1f, 100, nullptr, 0, 0, b_ih_l1f, b_hh_l1f, -1, pkhh, 16, idx); break;
    case 3: pack_body(w_ih_l1f, 200, nullptr, 0, 0, b_ih_l1f, b_hh_l1f, 200, pkxg, 28, idx); break;
    case 4: pack_body(w_ih_l1b, 200, nullptr, 0, 0, b_ih_l1b, b_hh_l1b, 200, pk1b, 28, idx); break;
    default:
      if (idx < Bsz * Tt * IN_) {
        int e = idx % IN_, bt = idx / IN_;
        int t = bt % Tt, b = bt / Tt;
        xT[((size_t)t * Bsz + b) * IN_ + e] = f2bf(x[idx]);
      }
  }
}

// ------------- layer 0 scan (grid = 128 x 2 dirs, 1024 thr) -----------------
__global__ __launch_bounds__(1024, 1) void lstm_l0(
    const unsigned short* __restrict__ xT,
    const unsigned short* __restrict__ pk_f, const unsigned short* __restrict__ pk_b,
    unsigned short* __restrict__ h0fT, unsigned short* __restrict__ h0bT) {
  __shared__ __align__(16) short A_s[2][16][16][8];  // [buf][kg][m16][jj], K=128

  const int tid = threadIdx.x;
  const int lane = tid & 63, w = tid >> 6;       // 16 waves
  const int q = lane >> 4, l16 = lane & 15;
  const int b0 = blockIdx.x * MB;
  const int dir = blockIdx.y;
  const unsigned short* pk = dir ? pk_b : pk_f;
  unsigned short* hT = dir ? h0bT : h0fT;

  for (int i = tid; i < 2 * 16 * 16 * 8; i += 1024) ((short*)A_s)[i] = 0;

  const int mtA = w, mtB = w + 16;
  const bool bvalid = (mtB < NT);
  bf16x8 wfA[4], wfB[4];
#pragma unroll
  for (int kt = 0; kt < 4; ++kt) {
    wfA[kt] = *(const bf16x8*)(pk + ((size_t)(kt * 4 + q) * NP + mtA * 16 + l16) * 8);
    wfB[kt] = *(const bf16x8*)(pk + ((size_t)(kt * 4 + q) * NP + mtB * 16 + l16) * 8);
  }
  float c = 0.f;
  const bool up = (l16 >= 8);
  const int mm = l16 & 7;
  const int j = (up ? mtB : mtA) * 4 + q;
  const bool valid = up ? bvalid : true;
  const int xm = tid / IN_, xe = tid - xm * IN_;              // x loader (tid<40)
  const int sm = tid / 25, sj = (tid - (tid / 25) * 25) * 4;  // h store (tid<200)
  __syncthreads();
  if (tid < 16) {  // bias-one col k=105 (kg13,jj1), both bufs
    A_s[0][13][tid][1] = (short)f2bf(1.f);
    A_s[1][13][tid][1] = (short)f2bf(1.f);
  }
  if (tid < MB * IN_) {  // x(t_first) -> buf0
    int t0 = dir ? (Tt - 1) : 0;
    int k = 100 + xe;
    A_s[0][k >> 3][xm][k & 7] = (short)xT[((size_t)t0 * Bsz + b0 + xm) * IN_ + xe];
  }
  __syncthreads();

  int p = 0;
  for (int step = 0; step < Tt; ++step) {
    const int t = dir ? (Tt - 1 - step) : step;
    if (step > 0 && tid < 200) {  // coalesced store of h(prev) from buf p
      int tp = dir ? (t + 1) : (t - 1);
      uint2 hv = *(const uint2*)&A_s[p][sj >> 3][sm][sj & 7];
      *(uint2*)(hT + ((size_t)tp * Bsz + b0 + sm) * H + sj) = hv;
    }
    unsigned short xn = 0;
    const bool do_x = (tid < MB * IN_) && (step < Tt - 1);
    if (do_x) {
      int tn = dir ? (t - 1) : (t + 1);
      xn = xT[((size_t)tn * Bsz + b0 + xm) * IN_ + xe];
    }
    bf16x8 hfrag[4];
#pragma unroll
    for (int kt = 0; kt < 4; ++kt) hfrag[kt] = *(const bf16x8*)A_s[p][kt * 4 + q][l16];
    f32x4 accA = (f32x4){0.f, 0.f, 0.f, 0.f};
    f32x4 accB = (f32x4){0.f, 0.f, 0.f, 0.f};
#pragma unroll
    for (int kt = 0; kt < 4; ++kt)
      accA = __builtin_amdgcn_mfma_f32_16x16x32_bf16(wfA[kt], hfrag[kt], accA, 0, 0, 0);
    if (bvalid) {
#pragma unroll
      for (int kt = 0; kt < 4; ++kt)
        accB = __builtin_amdgcn_mfma_f32_16x16x32_bf16(wfB[kt], hfrag[kt], accB, 0, 0, 0);
    }
    // exec-safe spread: every lane swizzles unconditionally, then selects
    float pb0 = partner8(accB[0]), pb1 = partner8(accB[1]);
    float pb2 = partner8(accB[2]), pb3 = partner8(accB[3]);
    float g0 = up ? pb0 : accA[0];
    float g1 = up ? pb1 : accA[1];
    float g2 = up ? pb2 : accA[2];
    float g3 = up ? pb3 : accA[3];
    float cc = sigm(g1) * c + sigm(g0) * tanhf_(g2);
    c = cc;
    float h = sigm(g3) * tanhf_(cc);
    if (valid) A_s[1 - p][j >> 3][mm][j & 7] = (short)f2bf(h);
    if (do_x) {
      int k = 100 + xe;
      A_s[1 - p][k >> 3][xm][k & 7] = (short)xn;
    }
    __syncthreads();
    p ^= 1;
  }
  if (tid < 200) {  // final h
    int tl = dir ? 0 : (Tt - 1);
    uint2 hv = *(const uint2*)&A_s[p][sj >> 3][sm][sj & 7];
    *(uint2*)(hT + ((size_t)tl * Bsz + b0 + sm) * H + sj) = hv;
  }
}

// ---- xgT[t*1024+b][400] = [h0f|h0b] @ W_ih_l1f^T + bias (fp16, interleaved) --
__global__ __launch_bounds__(256, 2) void gemm_xg(
    const unsigned short* __restrict__ h0fT, const unsigned short* __restrict__ h0bT,
    const unsigned short* __restrict__ pkw, __half* __restrict__ xg) {
  __shared__ __align__(16) short A_s[28][64][8];  // K=224 aug (k=200 bias-one)
  __shared__ __align__(16) short B_s[28][64][8];
  const int tid = threadIdx.x;
  const int lane = tid & 63, w = tid >> 6;
  const int q = lane >> 4, l16 = lane & 15;
  const int r0 = blockIdx.x * 64;          // rows r = t*1024+b
  const size_t base = (size_t)r0 * H;

  for (int i = tid; i < 3 * 64 * 8; i += 256) {  // kg 25..27: zero + bias-one
    int jj = i & 7, gl = i >> 9;
    ((short*)&A_s[25][0][0])[i] = (short)((gl == 0 && jj == 0) ? f2bf(1.f) : 0);
  }
  for (int r = 0; r < 7; ++r) {  // stage h0f (k=0..99) and h0b (k=100..199)
    int idx = tid + 256 * r;
    if (idx < 1600) {
      int m = idx / 25, j0 = (idx - (idx / 25) * 25) * 4;
      *(uint2*)&A_s[j0 >> 3][m][j0 & 7] = *(const uint2*)(h0fT + base + m * H + j0);
      int k = 100 + j0;
      *(uint2*)&A_s[k >> 3][m][k & 7] = *(const uint2*)(h0bT + base + m * H + j0);
    }
  }
  __syncthreads();

  for (int nb = 0; nb < 7; ++nb) {
    for (int cc = tid; cc < 28 * 64; cc += 256) {
      int g = cc >> 6, col = cc & 63;
      *(uint4*)B_s[g][col] = *(const uint4*)(pkw + ((size_t)g * NP + nb * 64 + col) * 8);
    }
    __syncthreads();
    f32x4 acc[4];
#pragma unroll
    for (int nt = 0; nt < 4; ++nt) acc[nt] = (f32x4){0.f, 0.f, 0.f, 0.f};
#pragma unroll
    for (int kt = 0; kt < 7; ++kt) {
      bf16x8 af = *(const bf16x8*)A_s[kt * 4 + q][w * 16 + l16];
#pragma unroll
      for (int nt = 0; nt < 4; ++nt) {
        bf16x8 bf = *(const bf16x8*)B_s[kt * 4 + q][nt * 16 + l16];
        acc[nt] = __builtin_amdgcn_mfma_f32_16x16x32_bf16(af, bf, acc[nt], 0, 0, 0);
      }
    }
#pragma unroll
    for (int nt = 0; nt < 4; ++nt) {
      int col = nb * 64 + nt * 16 + l16;
      if (col < G) {
#pragma unroll
        for (int r = 0; r < 4; ++r) {
          int row = r0 + w * 16 + q * 4 + r;
          xg[(size_t)row * G + col] = __float2half(acc[nt][r]);
        }
      }
    }
    __syncthreads();
  }
}

// ---- layer 1: fwd scan + bwd single step + FC + softmax (128 blk, 1024 thr) --
__global__ __launch_bounds__(1024, 1) void lstm_l1(
    const unsigned short* __restrict__ h0fT, const unsigned short* __restrict__ h0bT,
    const unsigned short* __restrict__ pk_hh, const unsigned short* __restrict__ pk1b,
    const __half* __restrict__ xg,
    const float* __restrict__ fc_w, const float* __restrict__ fc_b,
    float* __restrict__ out) {
  __shared__ __align__(16) short A_s[2][16][16][8];      // h1, K=128
  __shared__ __align__(16) short A2_s[28][16][8];        // epilogue [h0|1] K=224
  __shared__ __align__(8) unsigned short xg_s[2][MB * XGP];
  __shared__ float hf_s[MB][H];
  __shared__ float hb_s[MB][H];
  __shared__ float fcw_s[3 * D1];
  __shared__ float fcb_s[3];
  __shared__ float logit_s[MB][3];

  const int tid = threadIdx.x;
  const int lane = tid & 63, w = tid >> 6;   // 16 waves
  const int q = lane >> 4, l16 = lane & 15;
  const int b0 = blockIdx.x * MB;
  const uint2* xg2 = (const uint2*)xg;       // 100 uint2 per row

  for (int i = tid; i < 2 * 16 * 16 * 8; i += 1024) ((short*)A_s)[i] = 0;
  for (int i = tid; i < 25 * 16 * 8; i += 1024) ((short*)A2_s)[i] = 0;  // kg 0..24
  for (int i = tid; i < 3 * 16 * 8; i += 1024) {  // A2 kg25..27 zero + bias-one
    int jj = i & 7, gl = i >> 7;
    ((short*)&A2_s[25][0][0])[i] = (short)((gl == 0 && jj == 0) ? f2bf(1.f) : 0);
  }
  for (int i = tid; i < 3 * D1; i += 1024) fcw_s[i] = fc_w[i];
  if (tid < 3) fcb_s[tid] = fc_b[tid];
  // stage xg(t=0) -> buf0 (8 rows x 100 uint2)
  if (tid < MB * 100) {
    int m = tid / 100, cu = tid - (tid / 100) * 100;
    *(uint2*)&xg_s[0][m * XGP + cu * 4] = xg2[((size_t)b0 + m) * 100 + cu];
  }

  const int mtA = w, mtB = w + 16;
  const bool bvalid = (mtB < NT);
  bf16x8 wfA[4], wfB[4];
#pragma unroll
  for (int kt = 0; kt < 4; ++kt) {
    wfA[kt] = *(const bf16x8*)(pk_hh + ((size_t)(kt * 4 + q) * NP + mtA * 16 + l16) * 8);
    wfB[kt] = *(const bf16x8*)(pk_hh + ((size_t)(kt * 4 + q) * NP + mtB * 16 + l16) * 8);
  }
  float c = 0.f;
  const bool up = (l16 >= 8);
  const int mm = l16 & 7;
  const int j = (up ? mtB : mtA) * 4 + q;
  const bool valid = up ? bvalid : true;
  // depth-2 xg prefetch pipeline (preA holds t+1)
  const bool pvld = (tid < MB * 100);
  const int pm = tid / 100, pc = tid - (tid / 100) * 100;
  uint2 preA = {0, 0};
  if (pvld) preA = xg2[((size_t)Bsz + b0 + pm) * 100 + pc];  // t=1
  __syncthreads();

  int p = 0;
  for (int t = 0; t < Tt; ++t) {
    uint2 preB = preA;  // initialized (kills the t=Tt-2 UB read)
    if (t < Tt - 2 && pvld)
      preB = xg2[((size_t)(t + 2) * Bsz + b0 + pm) * 100 + pc];
    // acc init from xg (gates i,f,g,o of (m=mm, j=mt*4+q))
    uint2 xa = *(const uint2*)&xg_s[p][mm * XGP + 4 * (mtA * 4 + q)];
    float2 a01 = __half22float2(*(const __half2*)&xa.x);
    float2 a23 = __half22float2(*(const __half2*)&xa.y);
    f32x4 accA = (f32x4){a01.x, a01.y, a23.x, a23.y};
    f32x4 accB = (f32x4){0.f, 0.f, 0.f, 0.f};
    if (bvalid) {
      uint2 xb = *(const uint2*)&xg_s[p][mm * XGP + 4 * (mtB * 4 + q)];
      float2 b01 = __half22float2(*(const __half2*)&xb.x);
      float2 b23 = __half22float2(*(const __half2*)&xb.y);
      accB = (f32x4){b01.x, b01.y, b23.x, b23.y};
    }
    bf16x8 hfrag[4];
#pragma unroll
    for (int kt = 0; kt < 4; ++kt) hfrag[kt] = *(const bf16x8*)A_s[p][kt * 4 + q][l16];
#pragma unroll
    for (int kt = 0; kt < 4; ++kt)
      accA = __builtin_amdgcn_mfma_f32_16x16x32_bf16(wfA[kt], hfrag[kt], accA, 0, 0, 0);
    if (bvalid) {
#pragma unroll
      for (int kt = 0; kt < 4; ++kt)
        accB = __builtin_amdgcn_mfma_f32_16x16x32_bf16(wfB[kt], hfrag[kt], accB, 0, 0, 0);
    }
    float pb0 = partner8(accB[0]), pb1 = partner8(accB[1]);
    float pb2 = partner8(accB[2]), pb3 = partner8(accB[3]);
    float g0 = up ? pb0 : accA[0];
    float g1 = up ? pb1 : accA[1];
    float g2 = up ? pb2 : accA[2];
    float g3 = up ? pb3 : accA[3];
    float cc = sigm(g1) * c + sigm(g0) * tanhf_(g2);
    c = cc;
    float h = sigm(g3) * tanhf_(cc);
    if (valid) {
      A_s[1 - p][j >> 3][mm][j & 7] = (short)f2bf(h);
      if (t == Tt - 1) hf_s[mm][j] = h;
    }
    if (t < Tt - 1 && pvld) {  // drain preA (t+1) into the other buffer
      *(uint2*)&xg_s[1 - p][pm * XGP + pc * 4] = preA;
      preA = preB;
    }
    __syncthreads();
    p ^= 1;
  }

  // ---- layer-1 backward single step at t=T-1 (h=c=0) ----
  {
    const size_t base = ((size_t)(Tt - 1) * Bsz + b0) * H;
    if (tid < 200) {
      int m = tid / 25, j0 = (tid - (tid / 25) * 25) * 4;
      *(uint2*)&A2_s[j0 >> 3][m][j0 & 7] = *(const uint2*)(h0fT + base + m * H + j0);
      int k = 100 + j0;
      *(uint2*)&A2_s[k >> 3][m][k & 7] = *(const uint2*)(h0bT + base + m * H + j0);
    }
  }
  __syncthreads();
  {
    f32x4 accA = (f32x4){0.f, 0.f, 0.f, 0.f};
    f32x4 accB = (f32x4){0.f, 0.f, 0.f, 0.f};
#pragma unroll
    for (int kt = 0; kt < 7; ++kt) {
      bf16x8 hf = *(const bf16x8*)A2_s[kt * 4 + q][l16];
      bf16x8 wfa = *(const bf16x8*)(pk1b + ((size_t)(kt * 4 + q) * NP + mtA * 16 + l16) * 8);
      accA = __builtin_amdgcn_mfma_f32_16x16x32_bf16(wfa, hf, accA, 0, 0, 0);
      if (bvalid) {
        bf16x8 wfb = *(const bf16x8*)(pk1b + ((size_t)(kt * 4 + q) * NP + mtB * 16 + l16) * 8);
        accB = __builtin_amdgcn_mfma_f32_16x16x32_bf16(wfb, hf, accB, 0, 0, 0);
      }
    }
    float pb0 = partner8(accB[0]);
    float pb2 = partner8(accB[2]);
    float pb3 = partner8(accB[3]);
    float g0 = up ? pb0 : accA[0];
    float g2 = up ? pb2 : accA[2];
    float g3 = up ? pb3 : accA[3];
    float cc = sigm(g0) * tanhf_(g2);   // c_prev = 0
    if (valid) hb_s[mm][j] = sigm(g3) * tanhf_(cc);
  }
  __syncthreads();

  // ---- FC (3x200) + softmax ----
  if (tid < MB * 3) {
    int m = tid / 3, cls = tid - m * 3;
    float s = fcb_s[cls];
    for (int jj = 0; jj < H; ++jj) s += fcw_s[cls * D1 + jj] * hf_s[m][jj];
    for (int jj = 0; jj < H; ++jj) s += fcw_s[cls * D1 + H + jj] * hb_s[m][jj];
    logit_s[m][cls] = s;
  }
  __syncthreads();
  if (tid < MB) {
    float a = logit_s[tid][0], b = logit_s[tid][1], cc = logit_s[tid][2];
    float mx = fmaxf(a, fmaxf(b, cc));
    float e0 = __expf(a - mx), e1 = __expf(b - mx), e2 = __expf(cc - mx);
    float inv = 1.f / (e0 + e1 + e2);
    out[(b0 + tid) * 3 + 0] = e0 * inv;
    out[(b0 + tid) * 3 + 1] = e1 * inv;
    out[(b0 + tid) * 3 + 2] = e2 * inv;
  }
}

extern "C" void kernel_launch(void* const* d_in, const int* in_sizes, int n_in,
                              void* d_out, int out_size, void* d_ws, size_t ws_size,
                              hipStream_t stream) {
  const float* x        = (const float*)d_in[0];
  const float* w_ih_l0f = (const float*)d_in[1];
  const float* w_hh_l0f = (const float*)d_in[2];
  const float* b_ih_l0f = (const float*)d_in[3];
  const float* b_hh_l0f = (const float*)d_in[4];
  const float* w_ih_l0b = (const float*)d_in[5];
  const float* w_hh_l0b = (const float*)d_in[6];
  const float* b_ih_l0b = (const float*)d_in[7];
  const float* b_hh_l0b = (const float*)d_in[8];
  const float* w_ih_l1f = (const float*)d_in[9];
  const float* w_hh_l1f = (const float*)d_in[10];
  const float* b_ih_l1f = (const float*)d_in[11];
  const float* b_hh_l1f = (const float*)d_in[12];
  const float* w_ih_l1b = (const float*)d_in[13];
  // d_in[14] = w_hh_l1b unused (reverse dir at t=T-1 has h=0)
  const float* b_ih_l1b = (const float*)d_in[15];
  const float* b_hh_l1b = (const float*)d_in[16];
  const float* fc_w     = (const float*)d_in[17];
  const float* fc_b     = (const float*)d_in[18];

  unsigned short* h0fT = (unsigned short*)d_ws;
  unsigned short* h0bT = h0fT + (size_t)Tt * Bsz * H;
  __half* xgT          = (__half*)(h0bT + (size_t)Tt * Bsz * H);
  unsigned short* xT   = (unsigned short*)(xgT + (size_t)Tt * Bsz * G);
  unsigned short* pk0f = xT + (size_t)Tt * Bsz * IN_;
  unsigned short* pk0b = pk0f + 16 * NP * 8;
  unsigned short* pkhh = pk0b + 16 * NP * 8;
  unsigned short* pkxg = pkhh + 16 * NP * 8;
  unsigned short* pk1b = pkxg + 28 * NP * 8;

  pack_all<<<dim3(2560, 6), 256, 0, stream>>>(
      w_hh_l0f, w_ih_l0f, b_ih_l0f, b_hh_l0f,
      w_hh_l0b, w_ih_l0b, b_ih_l0b, b_hh_l0b,
      w_hh_l1f, b_ih_l1f, b_hh_l1f,
      w_ih_l1f, w_ih_l1b, b_ih_l1b, b_hh_l1b,
      x, pk0f, pk0b, pkhh, pkxg, pk1b, xT);

  lstm_l0<<<dim3(Bsz / MB, 2), 1024, 0, stream>>>(xT, pk0f, pk0b, h0fT, h0bT);
  gemm_xg<<<(Bsz * Tt) / 64, 256, 0, stream>>>(h0fT, h0bT, pkxg, xgT);
  lstm_l1<<<Bsz / MB, 1024, 0, stream>>>(h0fT, h0bT, pkhh, pk1b, xgT,
                                         fc_w, fc_b, (float*)d_out);
}

// Round 10
// 439.591 us; speedup vs baseline: 1.4277x; 1.0252x over previous
//
#include <hip/hip_runtime.h>
#include <hip/hip_fp16.h>

// LSTM_48850958024796 — R10: R9 (8-row spread, exec-safe ds_swizzle) minus
// per-step VALU overhead: register-direct per-lane xg prefetch (no LDS ring),
// running-pointer address arithmetic (no per-step 64-bit mul chains).
// Scan math (R3-proven): gates^T = W(A) @ [h|x|1]^T(B), cols gate-interleaved
// (n'=4j+gate): lane(q,l16) of tile mt holds gates i,f,g,o of (m=l16, j=mt*4+q)
// in acc[0..3]. 8 rows/block: lanes l16>=8 take tile B's gates from lane&~8 via
// unconditional ds_swizzle(0x17); each lane cell-updates exactly one (m,j).

typedef __attribute__((ext_vector_type(8))) short bf16x8;
typedef __attribute__((ext_vector_type(4))) float f32x4;

constexpr int Bsz = 1024, Tt = 128, IN_ = 5, H = 100, G = 400, D1 = 200;
constexpr int NP = 512;   // packed gate cols (32 tiles of 16)
constexpr int NT = 25;    // real tiles (400/16)
constexpr int MB = 8;     // batch rows per block

__device__ __forceinline__ float sigm(float x)   { return 1.f / (1.f + __expf(-x)); }
__device__ __forceinline__ float tanhf_(float x) { return 1.f - 2.f / (__expf(2.f * x) + 1.f); }
__device__ __forceinline__ unsigned short f2bf(float f) {
  unsigned u = __float_as_uint(f);
  u += 0x7fff + ((u >> 16) & 1);
  return (unsigned short)(u >> 16);
}
// every lane receives the value held by lane (lane & ~8); unconditional.
__device__ __forceinline__ float partner8(float v) {
  return __uint_as_float(
      (unsigned)__builtin_amdgcn_ds_swizzle((int)__float_as_uint(v), 0x17));
}

// packed col n' (0..511): j=n'>>2, gate=n'&3, src row n = gate*100+j; j>=100->0
__device__ __forceinline__ void pack_body(
    const float* wA, int KA, const float* wB, int KB, int kbo,
    const float* b1, const float* b2, int bias_k,
    unsigned short* dst, int Kg, int idx) {
  if (idx >= Kg * NP * 8) return;
  int jj = idx & 7, rest = idx >> 3;
  int np_ = rest % NP, g = rest / NP;
  int j = np_ >> 2, gate = np_ & 3;
  int k = g * 8 + jj;
  float v = 0.f;
  if (j < H) {
    int n = gate * H + j;
    if (k < KA) v = wA[n * KA + k];
    else if (KB > 0 && k >= kbo && k < kbo + KB) v = wB[n * KB + (k - kbo)];
    else if (k == bias_k) v = b1[n] + b2[n];
  }
  dst[idx] = f2bf(v);
}

__global__ void pack_all(
    const float* __restrict__ w_hh_l0f, const float* __restrict__ w_ih_l0f,
    const float* __restrict__ b_ih_l0f, const float* __restrict__ b_hh_l0f,
    const float* __restrict__ w_hh_l0b, const float* __restrict__ w_ih_l0b,
    const float* __restrict__ b_ih_l0b, const float* __restrict__ b_hh_l0b,
    const float* __restrict__ w_hh_l1f, const float* __restrict__ b_ih_l1f,
    const float* __restrict__ b_hh_l1f,
    const float* __restrict__ w_ih_l1f, const float* __restrict__ w_ih_l1b,
    const float* __restrict__ b_ih_l1b, const float* __restrict__ b_hh_l1b,
    const float* __restrict__ x,
    unsigned short* __restrict__ pk0f, unsigned short* __restrict__ pk0b,
    unsigned short* __restrict__ pkhh, unsigned short* __restrict__ pkxg,
    unsigned short* __restrict__ pk1b, unsigned short* __restrict__ xT) {
  int idx = blockIdx.x * 256 + threadIdx.x;
  switch (blockIdx.y) {
    case 0: pack_body(w_hh_l0f, 100, w_ih_l0f, 5, 100, b_ih_l0f, b_hh_l0f, 105, pk0f, 16, idx); break;
    case 1: pack_body(w_hh_l0b, 100, w_ih_l0b, 5, 100, b_ih_l0b, b_hh_l0b, 105, pk0b, 16, idx); break;
    case 2: pack_body(w_hh_l1f, 100, nullptr, 0, 0, b_ih_l1f, b_hh_l1f, -1, pkhh, 16, idx); break;
    case 3: pack_body(w_ih_l1f, 200, nullptr, 0, 0, b_ih_l1f, b_hh_l1f, 200, pkxg, 28, idx); break;
    case 4: pack_body(w_ih_l1b, 200, nullptr, 0, 0, b_ih_l1b, b_hh_l1b, 200, pk1b, 28, idx); break;
    default:
      if (idx < Bsz * Tt * IN_) {
        int e = idx % IN_, bt = idx / IN_;
        int t = bt % Tt, b = bt / Tt;
        xT[((size_t)t * Bsz + b) * IN_ + e] = f2bf(x[idx]);
      }
  }
}

// ------------- layer 0 scan (grid = 128 x 2 dirs, 1024 thr) -----------------
__global__ __launch_bounds__(1024, 1) void lstm_l0(
    const unsigned short* __restrict__ xT,
    const unsigned short* __restrict__ pk_f, const unsigned short* __restrict__ pk_b,
    unsigned short* __restrict__ h0fT, unsigned short* __restrict__ h0bT) {
  __shared__ __align__(16) short A_s[2][16][16][8];  // [buf][kg][m16][jj], K=128

  const int tid = threadIdx.x;
  const int lane = tid & 63, w = tid >> 6;       // 16 waves
  const int q = lane >> 4, l16 = lane & 15;
  const int b0 = blockIdx.x * MB;
  const int dir = blockIdx.y;
  const unsigned short* pk = dir ? pk_b : pk_f;
  unsigned short* hT = dir ? h0bT : h0fT;

  for (int i = tid; i < 2 * 16 * 16 * 8; i += 1024) ((short*)A_s)[i] = 0;

  const int mtA = w, mtB = w + 16;
  const bool bvalid = (mtB < NT);
  bf16x8 wfA[4], wfB[4];
#pragma unroll
  for (int kt = 0; kt < 4; ++kt) {
    wfA[kt] = *(const bf16x8*)(pk + ((size_t)(kt * 4 + q) * NP + mtA * 16 + l16) * 8);
    wfB[kt] = *(const bf16x8*)(pk + ((size_t)(kt * 4 + q) * NP + mtB * 16 + l16) * 8);
  }
  float c = 0.f;
  const bool up = (l16 >= 8);
  const int mm = l16 & 7;
  const int j = (up ? mtB : mtA) * 4 + q;
  const bool valid = up ? bvalid : true;
  const int xm = tid / IN_, xe = tid - xm * IN_;              // x loader (tid<40)
  const int sm = tid / 25, sj = (tid - (tid / 25) * 25) * 4;  // h store (tid<200)
  // running pointers (stride add per step instead of 64-bit recompute)
  const unsigned short* xp =
      xT + ((size_t)(dir ? Tt - 2 : 1) * Bsz + b0 + xm) * IN_ + xe;
  const int xstride = dir ? -(Bsz * IN_) : (Bsz * IN_);
  unsigned short* hp =
      hT + ((size_t)(dir ? Tt - 1 : 0) * Bsz + b0 + sm) * H + sj;
  const int hstride = dir ? -(Bsz * H) : (Bsz * H);
  __syncthreads();
  if (tid < 16) {  // bias-one col k=105 (kg13,jj1), both bufs
    A_s[0][13][tid][1] = (short)f2bf(1.f);
    A_s[1][13][tid][1] = (short)f2bf(1.f);
  }
  if (tid < MB * IN_) {  // x(t_first) -> buf0
    int t0 = dir ? (Tt - 1) : 0;
    int k = 100 + xe;
    A_s[0][k >> 3][xm][k & 7] = (short)xT[((size_t)t0 * Bsz + b0 + xm) * IN_ + xe];
  }
  __syncthreads();

  int p = 0;
  for (int step = 0; step < Tt; ++step) {
    if (step > 0 && tid < 200) {  // coalesced store of h(prev) from buf p
      uint2 hv = *(const uint2*)&A_s[p][sj >> 3][sm][sj & 7];
      *(uint2*)hp = hv;
      hp += hstride;
    }
    unsigned short xn = 0;
    const bool do_x = (tid < MB * IN_) && (step < Tt - 1);
    if (do_x) { xn = *xp; xp += xstride; }
    bf16x8 hfrag[4];
#pragma unroll
    for (int kt = 0; kt < 4; ++kt) hfrag[kt] = *(const bf16x8*)A_s[p][kt * 4 + q][l16];
    f32x4 accA = (f32x4){0.f, 0.f, 0.f, 0.f};
    f32x4 accB = (f32x4){0.f, 0.f, 0.f, 0.f};
#pragma unroll
    for (int kt = 0; kt < 4; ++kt)
      accA = __builtin_amdgcn_mfma_f32_16x16x32_bf16(wfA[kt], hfrag[kt], accA, 0, 0, 0);
    if (bvalid) {
#pragma unroll
      for (int kt = 0; kt < 4; ++kt)
        accB = __builtin_amdgcn_mfma_f32_16x16x32_bf16(wfB[kt], hfrag[kt], accB, 0, 0, 0);
    }
    // exec-safe spread: every lane swizzles unconditionally, then selects
    float pb0 = partner8(accB[0]), pb1 = partner8(accB[1]);
    float pb2 = partner8(accB[2]), pb3 = partner8(accB[3]);
    float g0 = up ? pb0 : accA[0];
    float g1 = up ? pb1 : accA[1];
    float g2 = up ? pb2 : accA[2];
    float g3 = up ? pb3 : accA[3];
    float cc = sigm(g1) * c + sigm(g0) * tanhf_(g2);
    c = cc;
    float h = sigm(g3) * tanhf_(cc);
    if (valid) A_s[1 - p][j >> 3][mm][j & 7] = (short)f2bf(h);
    if (do_x) {
      int k = 100 + xe;
      A_s[1 - p][k >> 3][xm][k & 7] = (short)xn;
    }
    __syncthreads();
    p ^= 1;
  }
  if (tid < 200) *(uint2*)hp = *(const uint2*)&A_s[p][sj >> 3][sm][sj & 7];  // final h
}

// ---- xgT[t*1024+b][400] = [h0f|h0b] @ W_ih_l1f^T + bias (fp16, interleaved) --
__global__ __launch_bounds__(256, 2) void gemm_xg(
    const unsigned short* __restrict__ h0fT, const unsigned short* __restrict__ h0bT,
    const unsigned short* __restrict__ pkw, __half* __restrict__ xg) {
  __shared__ __align__(16) short A_s[28][64][8];  // K=224 aug (k=200 bias-one)
  __shared__ __align__(16) short B_s[28][64][8];
  const int tid = threadIdx.x;
  const int lane = tid & 63, w = tid >> 6;
  const int q = lane >> 4, l16 = lane & 15;
  const int r0 = blockIdx.x * 64;          // rows r = t*1024+b
  const size_t base = (size_t)r0 * H;

  for (int i = tid; i < 3 * 64 * 8; i += 256) {  // kg 25..27: zero + bias-one
    int jj = i & 7, gl = i >> 9;
    ((short*)&A_s[25][0][0])[i] = (short)((gl == 0 && jj == 0) ? f2bf(1.f) : 0);
  }
  for (int r = 0; r < 7; ++r) {  // stage h0f (k=0..99) and h0b (k=100..199)
    int idx = tid + 256 * r;
    if (idx < 1600) {
      int m = idx / 25, j0 = (idx - (idx / 25) * 25) * 4;
      *(uint2*)&A_s[j0 >> 3][m][j0 & 7] = *(const uint2*)(h0fT + base + m * H + j0);
      int k = 100 + j0;
      *(uint2*)&A_s[k >> 3][m][k & 7] = *(const uint2*)(h0bT + base + m * H + j0);
    }
  }
  __syncthreads();

  for (int nb = 0; nb < 7; ++nb) {
    for (int cc = tid; cc < 28 * 64; cc += 256) {
      int g = cc >> 6, col = cc & 63;
      *(uint4*)B_s[g][col] = *(const uint4*)(pkw + ((size_t)g * NP + nb * 64 + col) * 8);
    }
    __syncthreads();
    f32x4 acc[4];
#pragma unroll
    for (int nt = 0; nt < 4; ++nt) acc[nt] = (f32x4){0.f, 0.f, 0.f, 0.f};
#pragma unroll
    for (int kt = 0; kt < 7; ++kt) {
      bf16x8 af = *(const bf16x8*)A_s[kt * 4 + q][w * 16 + l16];
#pragma unroll
      for (int nt = 0; nt < 4; ++nt) {
        bf16x8 bf = *(const bf16x8*)B_s[kt * 4 + q][nt * 16 + l16];
        acc[nt] = __builtin_amdgcn_mfma_f32_16x16x32_bf16(af, bf, acc[nt], 0, 0, 0);
      }
    }
#pragma unroll
    for (int nt = 0; nt < 4; ++nt) {
      int col = nb * 64 + nt * 16 + l16;
      if (col < G) {
#pragma unroll
        for (int r = 0; r < 4; ++r) {
          int row = r0 + w * 16 + q * 4 + r;
          xg[(size_t)row * G + col] = __float2half(acc[nt][r]);
        }
      }
    }
    __syncthreads();
  }
}

// ---- layer 1: fwd scan + bwd single step + FC + softmax (128 blk, 1024 thr) --
__global__ __launch_bounds__(1024, 1) void lstm_l1(
    const unsigned short* __restrict__ h0fT, const unsigned short* __restrict__ h0bT,
    const unsigned short* __restrict__ pk_hh, const unsigned short* __restrict__ pk1b,
    const __half* __restrict__ xg,
    const float* __restrict__ fc_w, const float* __restrict__ fc_b,
    float* __restrict__ out) {
  __shared__ __align__(16) short A_s[2][16][16][8];      // h1, K=128
  __shared__ __align__(16) short A2_s[28][16][8];        // epilogue [h0|1] K=224
  __shared__ float hf_s[MB][H];
  __shared__ float hb_s[MB][H];
  __shared__ float fcw_s[3 * D1];
  __shared__ float fcb_s[3];
  __shared__ float logit_s[MB][3];

  const int tid = threadIdx.x;
  const int lane = tid & 63, w = tid >> 6;   // 16 waves
  const int q = lane >> 4, l16 = lane & 15;
  const int b0 = blockIdx.x * MB;
  const uint2* xg2 = (const uint2*)xg;       // 100 uint2 per (t,b) row

  for (int i = tid; i < 2 * 16 * 16 * 8; i += 1024) ((short*)A_s)[i] = 0;
  for (int i = tid; i < 25 * 16 * 8; i += 1024) ((short*)A2_s)[i] = 0;  // kg 0..24
  for (int i = tid; i < 3 * 16 * 8; i += 1024) {  // A2 kg25..27 zero + bias-one
    int jj = i & 7, gl = i >> 7;
    ((short*)&A2_s[25][0][0])[i] = (short)((gl == 0 && jj == 0) ? f2bf(1.f) : 0);
  }
  for (int i = tid; i < 3 * D1; i += 1024) fcw_s[i] = fc_w[i];
  if (tid < 3) fcb_s[tid] = fc_b[tid];

  const int mtA = w, mtB = w + 16;
  const bool bvalid = (mtB < NT);
  bf16x8 wfA[4], wfB[4];
#pragma unroll
  for (int kt = 0; kt < 4; ++kt) {
    wfA[kt] = *(const bf16x8*)(pk_hh + ((size_t)(kt * 4 + q) * NP + mtA * 16 + l16) * 8);
    wfB[kt] = *(const bf16x8*)(pk_hh + ((size_t)(kt * 4 + q) * NP + mtB * 16 + l16) * 8);
  }
  float c = 0.f;
  const bool up = (l16 >= 8);
  const int mm = l16 & 7;
  const int j = (up ? mtB : mtA) * 4 + q;
  const bool valid = up ? bvalid : true;
  // register-direct xg prefetch: each lane loads its OWN gate-uint2 for both
  // tiles (row b0+mm, cols jA/jB). jB>=100 for bvalid==false lanes reads past
  // the row (<=224B past xg's end at t=127) into the adjacent ws region —
  // harmless, values unused. Running pointers: +102400 uint2 per t.
  const int jA = mtA * 4 + q;
  const int jB = mtB * 4 + q;
  const uint2* xgpA = xg2 + (size_t)(b0 + mm) * 100 + jA;
  const uint2* xgpB = xg2 + (size_t)(b0 + mm) * 100 + jB;
  uint2 xgCurA = xgpA[0], xgCurB = xgpB[0];  // t=0
  xgpA += Bsz * 100; xgpB += Bsz * 100;
  __syncthreads();

  int p = 0;
  for (int t = 0; t < Tt; ++t) {
    uint2 xgNxtA = xgCurA, xgNxtB = xgCurB;
    if (t < Tt - 1) {
      xgNxtA = *xgpA; xgNxtB = *xgpB;
      xgpA += Bsz * 100; xgpB += Bsz * 100;
    }
    // acc init from xg (gates i,f,g,o of (m=mm, j))
    float2 a01 = __half22float2(*(const __half2*)&xgCurA.x);
    float2 a23 = __half22float2(*(const __half2*)&xgCurA.y);
    float2 b01 = __half22float2(*(const __half2*)&xgCurB.x);
    float2 b23 = __half22float2(*(const __half2*)&xgCurB.y);
    f32x4 accA = (f32x4){a01.x, a01.y, a23.x, a23.y};
    f32x4 accB = (f32x4){b01.x, b01.y, b23.x, b23.y};
    bf16x8 hfrag[4];
#pragma unroll
    for (int kt = 0; kt < 4; ++kt) hfrag[kt] = *(const bf16x8*)A_s[p][kt * 4 + q][l16];
#pragma unroll
    for (int kt = 0; kt < 4; ++kt)
      accA = __builtin_amdgcn_mfma_f32_16x16x32_bf16(wfA[kt], hfrag[kt], accA, 0, 0, 0);
    if (bvalid) {
#pragma unroll
      for (int kt = 0; kt < 4; ++kt)
        accB = __builtin_amdgcn_mfma_f32_16x16x32_bf16(wfB[kt], hfrag[kt], accB, 0, 0, 0);
    }
    float pb0 = partner8(accB[0]), pb1 = partner8(accB[1]);
    float pb2 = partner8(accB[2]), pb3 = partner8(accB[3]);
    float g0 = up ? pb0 : accA[0];
    float g1 = up ? pb1 : accA[1];
    float g2 = up ? pb2 : accA[2];
    float g3 = up ? pb3 : accA[3];
    float cc = sigm(g1) * c + sigm(g0) * tanhf_(g2);
    c = cc;
    float h = sigm(g3) * tanhf_(cc);
    if (valid) {
      A_s[1 - p][j >> 3][mm][j & 7] = (short)f2bf(h);
      if (t == Tt - 1) hf_s[mm][j] = h;
    }
    xgCurA = xgNxtA; xgCurB = xgNxtB;
    __syncthreads();
    p ^= 1;
  }

  // ---- layer-1 backward single step at t=T-1 (h=c=0) ----
  {
    const size_t base = ((size_t)(Tt - 1) * Bsz + b0) * H;
    if (tid < 200) {
      int m = tid / 25, j0 = (tid - (tid / 25) * 25) * 4;
      *(uint2*)&A2_s[j0 >> 3][m][j0 & 7] = *(const uint2*)(h0fT + base + m * H + j0);
      int k = 100 + j0;
      *(uint2*)&A2_s[k >> 3][m][k & 7] = *(const uint2*)(h0bT + base + m * H + j0);
    }
  }
  __syncthreads();
  {
    f32x4 accA = (f32x4){0.f, 0.f, 0.f, 0.f};
    f32x4 accB = (f32x4){0.f, 0.f, 0.f, 0.f};
#pragma unroll
    for (int kt = 0; kt < 7; ++kt) {
      bf16x8 hf = *(const bf16x8*)A2_s[kt * 4 + q][l16];
      bf16x8 wfa = *(const bf16x8*)(pk1b + ((size_t)(kt * 4 + q) * NP + mtA * 16 + l16) * 8);
      accA = __builtin_amdgcn_mfma_f32_16x16x32_bf16(wfa, hf, accA, 0, 0, 0);
      if (bvalid) {
        bf16x8 wfb = *(const bf16x8*)(pk1b + ((size_t)(kt * 4 + q) * NP + mtB * 16 + l16) * 8);
        accB = __builtin_amdgcn_mfma_f32_16x16x32_bf16(wfb, hf, accB, 0, 0, 0);
      }
    }
    float pb0 = partner8(accB[0]);
    float pb2 = partner8(accB[2]);
    float pb3 = partner8(accB[3]);
    float g0 = up ? pb0 : accA[0];
    float g2 = up ? pb2 : accA[2];
    float g3 = up ? pb3 : accA[3];
    float cc = sigm(g0) * tanhf_(g2);   // c_prev = 0
    if (valid) hb_s[mm][j] = sigm(g3) * tanhf_(cc);
  }
  __syncthreads();

  // ---- FC (3x200) + softmax ----
  if (tid < MB * 3) {
    int m = tid / 3, cls = tid - m * 3;
    float s = fcb_s[cls];
    for (int jj = 0; jj < H; ++jj) s += fcw_s[cls * D1 + jj] * hf_s[m][jj];
    for (int jj = 0; jj < H; ++jj) s += fcw_s[cls * D1 + H + jj] * hb_s[m][jj];
    logit_s[m][cls] = s;
  }
  __syncthreads();
  if (tid < MB) {
    float a = logit_s[tid][0], b = logit_s[tid][1], cc = logit_s[tid][2];
    float mx = fmaxf(a, fmaxf(b, cc));
    float e0 = __expf(a - mx), e1 = __expf(b - mx), e2 = __expf(cc - mx);
    float inv = 1.f / (e0 + e1 + e2);
    out[(b0 + tid) * 3 + 0] = e0 * inv;
    out[(b0 + tid) * 3 + 1] = e1 * inv;
    out[(b0 + tid) * 3 + 2] = e2 * inv;
  }
}

extern "C" void kernel_launch(void* const* d_in, const int* in_sizes, int n_in,
                              void* d_out, int out_size, void* d_ws, size_t ws_size,
                              hipStream_t stream) {
  const float* x        = (const float*)d_in[0];
  const float* w_ih_l0f = (const float*)d_in[1];
  const float* w_hh_l0f = (const float*)d_in[2];
  const float* b_ih_l0f = (const float*)d_in[3];
  const float* b_hh_l0f = (const float*)d_in[4];
  const float* w_ih_l0b = (const float*)d_in[5];
  const float* w_hh_l0b = (const float*)d_in[6];
  const float* b_ih_l0b = (const float*)d_in[7];
  const float* b_hh_l0b = (const float*)d_in[8];
  const float* w_ih_l1f = (const float*)d_in[9];
  const float* w_hh_l1f = (const float*)d_in[10];
  const float* b_ih_l1f = (const float*)d_in[11];
  const float* b_hh_l1f = (const float*)d_in[12];
  const float* w_ih_l1b = (const float*)d_in[13];
  // d_in[14] = w_hh_l1b unused (reverse dir at t=T-1 has h=0)
  const float* b_ih_l1b = (const float*)d_in[15];
  const float* b_hh_l1b = (const float*)d_in[16];
  const float* fc_w     = (const float*)d_in[17];
  const float* fc_b     = (const float*)d_in[18];

  unsigned short* h0fT = (unsigned short*)d_ws;
  unsigned short* h0bT = h0fT + (size_t)Tt * Bsz * H;
  __half* xgT          = (__half*)(h0bT + (size_t)Tt * Bsz * H);
  unsigned short* xT   = (unsigned short*)(xgT + (size_t)Tt * Bsz * G);
  unsigned short* pk0f = xT + (size_t)Tt * Bsz * IN_;
  unsigned short* pk0b = pk0f + 16 * NP * 8;
  unsigned short* pkhh = pk0b + 16 * NP * 8;
  unsigned short* pkxg = pkhh + 16 * NP * 8;
  unsigned short* pk1b = pkxg + 28 * NP * 8;

  pack_all<<<dim3(2560, 6), 256, 0, stream>>>(
      w_hh_l0f, w_ih_l0f, b_ih_l0f, b_hh_l0f,
      w_hh_l0b, w_ih_l0b, b_ih_l0b, b_hh_l0b,
      w_hh_l1f, b_ih_l1f, b_hh_l1f,
      w_ih_l1f, w_ih_l1b, b_ih_l1b, b_hh_l1b,
      x, pk0f, pk0b, pkhh, pkxg, pk1b, xT);

  lstm_l0<<<dim3(Bsz / MB, 2), 1024, 0, stream>>>(xT, pk0f, pk0b, h0fT, h0bT);
  gemm_xg<<<(Bsz * Tt) / 64, 256, 0, stream>>>(h0fT, h0bT, pkxg, xgT);
  lstm_l1<<<Bsz / MB, 1024, 0, stream>>>(h0fT, h0bT, pkhh, pk1b, xgT,
                                         fc_w, fc_b, (float*)d_out);
}

// Round 11
// 395.364 us; speedup vs baseline: 1.5874x; 1.1119x over previous
//
#include <hip/hip_runtime.h>
#include <hip/hip_fp16.h>

// LSTM_48850958024796 — R11: R10 scans + weight-stationary gemm_xg (1 barrier,
// register-resident weights, 16 waves), barrier_nv in scan loops, 2x unroll,
// l0 reads x directly (xT/pack-case-5 deleted).
// Scan math (R3-proven): gates^T = W(A) @ [h|x|1]^T(B), cols gate-interleaved
// (n'=4j+gate): lane(q,l16) of tile mt holds gates i,f,g,o of (m=l16, j=mt*4+q)
// in acc[0..3]. 8 rows/block: lanes l16>=8 take tile B's gates from lane&~8 via
// unconditional ds_swizzle(0x17); each lane cell-updates exactly one (m,j).

typedef __attribute__((ext_vector_type(8))) short bf16x8;
typedef __attribute__((ext_vector_type(4))) float f32x4;

constexpr int Bsz = 1024, Tt = 128, IN_ = 5, H = 100, G = 400, D1 = 200;
constexpr int NP = 512;   // packed gate cols (32 tiles of 16)
constexpr int NT = 25;    // real tiles (400/16)
constexpr int MB = 8;     // batch rows per block (scans)

__device__ __forceinline__ float sigm(float x)   { return 1.f / (1.f + __expf(-x)); }
__device__ __forceinline__ float tanhf_(float x) { return 1.f - 2.f / (__expf(2.f * x) + 1.f); }
__device__ __forceinline__ unsigned short f2bf(float f) {
  unsigned u = __float_as_uint(f);
  u += 0x7fff + ((u >> 16) & 1);
  return (unsigned short)(u >> 16);
}
// every lane receives the value held by lane (lane & ~8); unconditional.
__device__ __forceinline__ float partner8(float v) {
  return __uint_as_float(
      (unsigned)__builtin_amdgcn_ds_swizzle((int)__float_as_uint(v), 0x17));
}
// workgroup barrier without the compiler's vmcnt(0) drain (LDS-only wait);
// safe here: global-load results are vmcnt-guarded at USE, global stores are
// drained at kernel end (not read in-kernel).
__device__ __forceinline__ void barrier_nv() {
  asm volatile("s_waitcnt lgkmcnt(0)\n\ts_barrier" ::: "memory");
}

// packed col n' (0..511): j=n'>>2, gate=n'&3, src row n = gate*100+j; j>=100->0
__device__ __forceinline__ void pack_body(
    const float* wA, int KA, const float* wB, int KB, int kbo,
    const float* b1, const float* b2, int bias_k,
    unsigned short* dst, int Kg, int idx) {
  if (idx >= Kg * NP * 8) return;
  int jj = idx & 7, rest = idx >> 3;
  int np_ = rest % NP, g = rest / NP;
  int j = np_ >> 2, gate = np_ & 3;
  int k = g * 8 + jj;
  float v = 0.f;
  if (j < H) {
    int n = gate * H + j;
    if (k < KA) v = wA[n * KA + k];
    else if (KB > 0 && k >= kbo && k < kbo + KB) v = wB[n * KB + (k - kbo)];
    else if (k == bias_k) v = b1[n] + b2[n];
  }
  dst[idx] = f2bf(v);
}

__global__ void pack_all(
    const float* __restrict__ w_hh_l0f, const float* __restrict__ w_ih_l0f,
    const float* __restrict__ b_ih_l0f, const float* __restrict__ b_hh_l0f,
    const float* __restrict__ w_hh_l0b, const float* __restrict__ w_ih_l0b,
    const float* __restrict__ b_ih_l0b, const float* __restrict__ b_hh_l0b,
    const float* __restrict__ w_hh_l1f, const float* __restrict__ b_ih_l1f,
    const float* __restrict__ b_hh_l1f,
    const float* __restrict__ w_ih_l1f, const float* __restrict__ w_ih_l1b,
    const float* __restrict__ b_ih_l1b, const float* __restrict__ b_hh_l1b,
    unsigned short* __restrict__ pk0f, unsigned short* __restrict__ pk0b,
    unsigned short* __restrict__ pkhh, unsigned short* __restrict__ pkxg,
    unsigned short* __restrict__ pk1b) {
  int idx = blockIdx.x * 256 + threadIdx.x;
  switch (blockIdx.y) {
    case 0: pack_body(w_hh_l0f, 100, w_ih_l0f, 5, 100, b_ih_l0f, b_hh_l0f, 105, pk0f, 16, idx); break;
    case 1: pack_body(w_hh_l0b, 100, w_ih_l0b, 5, 100, b_ih_l0b, b_hh_l0b, 105, pk0b, 16, idx); break;
    case 2: pack_body(w_hh_l1f, 100, nullptr, 0, 0, b_ih_l1f, b_hh_l1f, -1, pkhh, 16, idx); break;
    case 3: pack_body(w_ih_l1f, 200, nullptr, 0, 0, b_ih_l1f, b_hh_l1f, 200, pkxg, 28, idx); break;
    default: pack_body(w_ih_l1b, 200, nullptr, 0, 0, b_ih_l1b, b_hh_l1b, 200, pk1b, 28, idx);
  }
}

// ------------- layer 0 scan (grid = 128 x 2 dirs, 1024 thr) -----------------
__global__ __launch_bounds__(1024, 1) void lstm_l0(
    const float* __restrict__ x,
    const unsigned short* __restrict__ pk_f, const unsigned short* __restrict__ pk_b,
    unsigned short* __restrict__ h0fT, unsigned short* __restrict__ h0bT) {
  __shared__ __align__(16) short A_s[2][16][16][8];  // [buf][kg][m16][jj], K=128

  const int tid = threadIdx.x;
  const int lane = tid & 63, w = tid >> 6;       // 16 waves
  const int q = lane >> 4, l16 = lane & 15;
  const int b0 = blockIdx.x * MB;
  const int dir = blockIdx.y;
  const unsigned short* pk = dir ? pk_b : pk_f;
  unsigned short* hT = dir ? h0bT : h0fT;

  for (int i = tid; i < 2 * 16 * 16 * 8; i += 1024) ((short*)A_s)[i] = 0;

  const int mtA = w, mtB = w + 16;
  const bool bvalid = (mtB < NT);
  bf16x8 wfA[4], wfB[4];
#pragma unroll
  for (int kt = 0; kt < 4; ++kt) {
    wfA[kt] = *(const bf16x8*)(pk + ((size_t)(kt * 4 + q) * NP + mtA * 16 + l16) * 8);
    wfB[kt] = *(const bf16x8*)(pk + ((size_t)(kt * 4 + q) * NP + mtB * 16 + l16) * 8);
  }
  float c = 0.f;
  const bool up = (l16 >= 8);
  const int mm = l16 & 7;
  const int j = (up ? mtB : mtA) * 4 + q;
  const bool valid = up ? bvalid : true;
  const int xm = tid / IN_, xe = tid - xm * IN_;              // x loader (tid<40)
  const int sm = tid / 25, sj = (tid - (tid / 25) * 25) * 4;  // h store (tid<200)
  // running pointers (stride add per step, no per-step 64-bit recompute)
  const float* xp = x + ((size_t)(b0 + xm) * Tt + (dir ? Tt - 2 : 1)) * IN_ + xe;
  const int xstride = dir ? -IN_ : IN_;
  unsigned short* hp =
      hT + ((size_t)(dir ? Tt - 1 : 0) * Bsz + b0 + sm) * H + sj;
  const int hstride = dir ? -(Bsz * H) : (Bsz * H);
  __syncthreads();
  if (tid < 16) {  // bias-one col k=105 (kg13,jj1), both bufs
    A_s[0][13][tid][1] = (short)f2bf(1.f);
    A_s[1][13][tid][1] = (short)f2bf(1.f);
  }
  if (tid < MB * IN_) {  // x(t_first) -> buf0, direct f32 read
    int t0 = dir ? (Tt - 1) : 0;
    int k = 100 + xe;
    A_s[0][k >> 3][xm][k & 7] =
        (short)f2bf(x[((size_t)(b0 + xm) * Tt + t0) * IN_ + xe]);
  }
  __syncthreads();

  int p = 0;
#pragma unroll 2
  for (int step = 0; step < Tt; ++step) {
    if (step > 0 && tid < 200) {  // coalesced store of h(prev) from buf p
      uint2 hv = *(const uint2*)&A_s[p][sj >> 3][sm][sj & 7];
      *(uint2*)hp = hv;
      hp += hstride;
    }
    float xn = 0.f;
    const bool do_x = (tid < MB * IN_) && (step < Tt - 1);
    if (do_x) { xn = *xp; xp += xstride; }
    bf16x8 hfrag[4];
#pragma unroll
    for (int kt = 0; kt < 4; ++kt) hfrag[kt] = *(const bf16x8*)A_s[p][kt * 4 + q][l16];
    f32x4 accA = (f32x4){0.f, 0.f, 0.f, 0.f};
    f32x4 accB = (f32x4){0.f, 0.f, 0.f, 0.f};
#pragma unroll
    for (int kt = 0; kt < 4; ++kt)
      accA = __builtin_amdgcn_mfma_f32_16x16x32_bf16(wfA[kt], hfrag[kt], accA, 0, 0, 0);
    if (bvalid) {
#pragma unroll
      for (int kt = 0; kt < 4; ++kt)
        accB = __builtin_amdgcn_mfma_f32_16x16x32_bf16(wfB[kt], hfrag[kt], accB, 0, 0, 0);
    }
    // exec-safe spread: every lane swizzles unconditionally, then selects
    float pb0 = partner8(accB[0]), pb1 = partner8(accB[1]);
    float pb2 = partner8(accB[2]), pb3 = partner8(accB[3]);
    float g0 = up ? pb0 : accA[0];
    float g1 = up ? pb1 : accA[1];
    float g2 = up ? pb2 : accA[2];
    float g3 = up ? pb3 : accA[3];
    float cc = sigm(g1) * c + sigm(g0) * tanhf_(g2);
    c = cc;
    float h = sigm(g3) * tanhf_(cc);
    if (valid) A_s[1 - p][j >> 3][mm][j & 7] = (short)f2bf(h);
    if (do_x) {
      int k = 100 + xe;
      A_s[1 - p][k >> 3][xm][k & 7] = (short)f2bf(xn);
    }
    barrier_nv();
    p ^= 1;
  }
  if (tid < 200) *(uint2*)hp = *(const uint2*)&A_s[p][sj >> 3][sm][sj & 7];  // final h
}

// ---- xgT[t*1024+b][400] = [h0f|h0b] @ W_ih_l1f^T + bias (fp16, interleaved) --
// Weight-stationary rewrite: weights as A-operand in regs (2 tiles x 7 kt per
// wave), 64 rows staged once in LDS as B, ONE barrier, 4 row-groups.
__global__ __launch_bounds__(1024, 1) void gemm_xg(
    const unsigned short* __restrict__ h0fT, const unsigned short* __restrict__ h0bT,
    const unsigned short* __restrict__ pkw, __half* __restrict__ xg) {
  __shared__ __align__(16) short B_s[28][64][8];  // K=224 aug (k=200 bias-one)
  const int tid = threadIdx.x;
  const int lane = tid & 63, w = tid >> 6;   // 16 waves
  const int q = lane >> 4, l16 = lane & 15;
  const int r0 = blockIdx.x * 64;            // rows r = t*1024+b
  const size_t base = (size_t)r0 * H;

  for (int i = tid; i < 3 * 64 * 8; i += 1024) {  // kg 25..27: zero + bias-one
    int jj = i & 7, gl = i >> 9;
    ((short*)&B_s[25][0][0])[i] = (short)((gl == 0 && jj == 0) ? f2bf(1.f) : 0);
  }
  for (int idx = tid; idx < 1600; idx += 1024) {  // h0f k=0..99, h0b k=100..199
    int m = idx / 25, j0 = (idx - (idx / 25) * 25) * 4;
    *(uint2*)&B_s[j0 >> 3][m][j0 & 7] = *(const uint2*)(h0fT + base + m * H + j0);
    int k = 100 + j0;
    *(uint2*)&B_s[k >> 3][m][k & 7] = *(const uint2*)(h0bT + base + m * H + j0);
  }

  const int mtA = w, mtB = w + 16;
  const bool bvalid = (mtB < NT);
  bf16x8 wfA[7], wfB[7];
#pragma unroll
  for (int kt = 0; kt < 7; ++kt) {
    wfA[kt] = *(const bf16x8*)(pkw + ((size_t)(kt * 4 + q) * NP + mtA * 16 + l16) * 8);
    wfB[kt] = *(const bf16x8*)(pkw + ((size_t)(kt * 4 + q) * NP + mtB * 16 + l16) * 8);
  }
  const int jA = mtA * 4 + q, jB = mtB * 4 + q;
  __syncthreads();

#pragma unroll
  for (int rg = 0; rg < 4; ++rg) {
    f32x4 accA = (f32x4){0.f, 0.f, 0.f, 0.f};
    f32x4 accB = (f32x4){0.f, 0.f, 0.f, 0.f};
#pragma unroll
    for (int kt = 0; kt < 7; ++kt) {
      bf16x8 hf = *(const bf16x8*)B_s[kt * 4 + q][rg * 16 + l16];
      accA = __builtin_amdgcn_mfma_f32_16x16x32_bf16(wfA[kt], hf, accA, 0, 0, 0);
      if (bvalid)
        accB = __builtin_amdgcn_mfma_f32_16x16x32_bf16(wfB[kt], hf, accB, 0, 0, 0);
    }
    const size_t row = (size_t)(r0 + rg * 16 + l16);
    {
      __half2 h01 = __floats2half2_rn(accA[0], accA[1]);
      __half2 h23 = __floats2half2_rn(accA[2], accA[3]);
      uint2 st; *(__half2*)&st.x = h01; *(__half2*)&st.y = h23;
      *(uint2*)(xg + row * G + 4 * jA) = st;
    }
    if (bvalid) {
      __half2 h01 = __floats2half2_rn(accB[0], accB[1]);
      __half2 h23 = __floats2half2_rn(accB[2], accB[3]);
      uint2 st; *(__half2*)&st.x = h01; *(__half2*)&st.y = h23;
      *(uint2*)(xg + row * G + 4 * jB) = st;
    }
  }
}

// ---- layer 1: fwd scan + bwd single step + FC + softmax (128 blk, 1024 thr) --
__global__ __launch_bounds__(1024, 1) void lstm_l1(
    const unsigned short* __restrict__ h0fT, const unsigned short* __restrict__ h0bT,
    const unsigned short* __restrict__ pk_hh, const unsigned short* __restrict__ pk1b,
    const __half* __restrict__ xg,
    const float* __restrict__ fc_w, const float* __restrict__ fc_b,
    float* __restrict__ out) {
  __shared__ __align__(16) short A_s[2][16][16][8];      // h1, K=128
  __shared__ __align__(16) short A2_s[28][16][8];        // epilogue [h0|1] K=224
  __shared__ float hf_s[MB][H];
  __shared__ float hb_s[MB][H];
  __shared__ float fcw_s[3 * D1];
  __shared__ float fcb_s[3];
  __shared__ float logit_s[MB][3];

  const int tid = threadIdx.x;
  const int lane = tid & 63, w = tid >> 6;   // 16 waves
  const int q = lane >> 4, l16 = lane & 15;
  const int b0 = blockIdx.x * MB;
  const uint2* xg2 = (const uint2*)xg;       // 100 uint2 per (t,b) row

  for (int i = tid; i < 2 * 16 * 16 * 8; i += 1024) ((short*)A_s)[i] = 0;
  for (int i = tid; i < 25 * 16 * 8; i += 1024) ((short*)A2_s)[i] = 0;  // kg 0..24
  for (int i = tid; i < 3 * 16 * 8; i += 1024) {  // A2 kg25..27 zero + bias-one
    int jj = i & 7, gl = i >> 7;
    ((short*)&A2_s[25][0][0])[i] = (short)((gl == 0 && jj == 0) ? f2bf(1.f) : 0);
  }
  for (int i = tid; i < 3 * D1; i += 1024) fcw_s[i] = fc_w[i];
  if (tid < 3) fcb_s[tid] = fc_b[tid];

  const int mtA = w, mtB = w + 16;
  const bool bvalid = (mtB < NT);
  bf16x8 wfA[4], wfB[4];
#pragma unroll
  for (int kt = 0; kt < 4; ++kt) {
    wfA[kt] = *(const bf16x8*)(pk_hh + ((size_t)(kt * 4 + q) * NP + mtA * 16 + l16) * 8);
    wfB[kt] = *(const bf16x8*)(pk_hh + ((size_t)(kt * 4 + q) * NP + mtB * 16 + l16) * 8);
  }
  float c = 0.f;
  const bool up = (l16 >= 8);
  const int mm = l16 & 7;
  const int j = (up ? mtB : mtA) * 4 + q;
  const bool valid = up ? bvalid : true;
  // register-direct xg prefetch with running pointers (+102400 uint2 per t);
  // invalid-lane jB reads land <=224B past xg (adjacent ws region), unused.
  const int jA = mtA * 4 + q;
  const int jB = mtB * 4 + q;
  const uint2* xgpA = xg2 + (size_t)(b0 + mm) * 100 + jA;
  const uint2* xgpB = xg2 + (size_t)(b0 + mm) * 100 + jB;
  uint2 xgCurA = xgpA[0], xgCurB = xgpB[0];  // t=0
  xgpA += Bsz * 100; xgpB += Bsz * 100;
  float h_last = 0.f;
  __syncthreads();

  int p = 0;
#pragma unroll 2
  for (int t = 0; t < Tt; ++t) {
    uint2 xgNxtA = xgCurA, xgNxtB = xgCurB;
    if (t < Tt - 1) {
      xgNxtA = *xgpA; xgNxtB = *xgpB;
      xgpA += Bsz * 100; xgpB += Bsz * 100;
    }
    // acc init from xg (gates i,f,g,o of (m=mm, j))
    float2 a01 = __half22float2(*(const __half2*)&xgCurA.x);
    float2 a23 = __half22float2(*(const __half2*)&xgCurA.y);
    float2 b01 = __half22float2(*(const __half2*)&xgCurB.x);
    float2 b23 = __half22float2(*(const __half2*)&xgCurB.y);
    f32x4 accA = (f32x4){a01.x, a01.y, a23.x, a23.y};
    f32x4 accB = (f32x4){b01.x, b01.y, b23.x, b23.y};
    bf16x8 hfrag[4];
#pragma unroll
    for (int kt = 0; kt < 4; ++kt) hfrag[kt] = *(const bf16x8*)A_s[p][kt * 4 + q][l16];
#pragma unroll
    for (int kt = 0; kt < 4; ++kt)
      accA = __builtin_amdgcn_mfma_f32_16x16x32_bf16(wfA[kt], hfrag[kt], accA, 0, 0, 0);
    if (bvalid) {
#pragma unroll
      for (int kt = 0; kt < 4; ++kt)
        accB = __builtin_amdgcn_mfma_f32_16x16x32_bf16(wfB[kt], hfrag[kt], accB, 0, 0, 0);
    }
    float pb0 = partner8(accB[0]), pb1 = partner8(accB[1]);
    float pb2 = partner8(accB[2]), pb3 = partner8(accB[3]);
    float g0 = up ? pb0 : accA[0];
    float g1 = up ? pb1 : accA[1];
    float g2 = up ? pb2 : accA[2];
    float g3 = up ? pb3 : accA[3];
    float cc = sigm(g1) * c + sigm(g0) * tanhf_(g2);
    c = cc;
    float h = sigm(g3) * tanhf_(cc);
    if (valid) A_s[1 - p][j >> 3][mm][j & 7] = (short)f2bf(h);
    h_last = h;
    xgCurA = xgNxtA; xgCurB = xgNxtB;
    barrier_nv();
    p ^= 1;
  }
  if (valid) hf_s[mm][j] = h_last;

  // ---- layer-1 backward single step at t=T-1 (h=c=0) ----
  {
    const size_t base = ((size_t)(Tt - 1) * Bsz + b0) * H;
    if (tid < 200) {
      int m = tid / 25, j0 = (tid - (tid / 25) * 25) * 4;
      *(uint2*)&A2_s[j0 >> 3][m][j0 & 7] = *(const uint2*)(h0fT + base + m * H + j0);
      int k = 100 + j0;
      *(uint2*)&A2_s[k >> 3][m][k & 7] = *(const uint2*)(h0bT + base + m * H + j0);
    }
  }
  __syncthreads();
  {
    f32x4 accA = (f32x4){0.f, 0.f, 0.f, 0.f};
    f32x4 accB = (f32x4){0.f, 0.f, 0.f, 0.f};
#pragma unroll
    for (int kt = 0; kt < 7; ++kt) {
      bf16x8 hf = *(const bf16x8*)A2_s[kt * 4 + q][l16];
      bf16x8 wfa = *(const bf16x8*)(pk1b + ((size_t)(kt * 4 + q) * NP + mtA * 16 + l16) * 8);
      accA = __builtin_amdgcn_mfma_f32_16x16x32_bf16(wfa, hf, accA, 0, 0, 0);
      if (bvalid) {
        bf16x8 wfb = *(const bf16x8*)(pk1b + ((size_t)(kt * 4 + q) * NP + mtB * 16 + l16) * 8);
        accB = __builtin_amdgcn_mfma_f32_16x16x32_bf16(wfb, hf, accB, 0, 0, 0);
      }
    }
    float pb0 = partner8(accB[0]);
    float pb2 = partner8(accB[2]);
    float pb3 = partner8(accB[3]);
    float g0 = up ? pb0 : accA[0];
    float g2 = up ? pb2 : accA[2];
    float g3 = up ? pb3 : accA[3];
    float cc = sigm(g0) * tanhf_(g2);   // c_prev = 0
    if (valid) hb_s[mm][j] = sigm(g3) * tanhf_(cc);
  }
  __syncthreads();

  // ---- FC (3x200) + softmax ----
  if (tid < MB * 3) {
    int m = tid / 3, cls = tid - m * 3;
    float s = fcb_s[cls];
    for (int jj = 0; jj < H; ++jj) s += fcw_s[cls * D1 + jj] * hf_s[m][jj];
    for (int jj = 0; jj < H; ++jj) s += fcw_s[cls * D1 + H + jj] * hb_s[m][jj];
    logit_s[m][cls] = s;
  }
  __syncthreads();
  if (tid < MB) {
    float a = logit_s[tid][0], b = logit_s[tid][1], cc = logit_s[tid][2];
    float mx = fmaxf(a, fmaxf(b, cc));
    float e0 = __expf(a - mx), e1 = __expf(b - mx), e2 = __expf(cc - mx);
    float inv = 1.f / (e0 + e1 + e2);
    out[(b0 + tid) * 3 + 0] = e0 * inv;
    out[(b0 + tid) * 3 + 1] = e1 * inv;
    out[(b0 + tid) * 3 + 2] = e2 * inv;
  }
}

extern "C" void kernel_launch(void* const* d_in, const int* in_sizes, int n_in,
                              void* d_out, int out_size, void* d_ws, size_t ws_size,
                              hipStream_t stream) {
  const float* x        = (const float*)d_in[0];
  const float* w_ih_l0f = (const float*)d_in[1];
  const float* w_hh_l0f = (const float*)d_in[2];
  const float* b_ih_l0f = (const float*)d_in[3];
  const float* b_hh_l0f = (const float*)d_in[4];
  const float* w_ih_l0b = (const float*)d_in[5];
  const float* w_hh_l0b = (const float*)d_in[6];
  const float* b_ih_l0b = (const float*)d_in[7];
  const float* b_hh_l0b = (const float*)d_in[8];
  const float* w_ih_l1f = (const float*)d_in[9];
  const float* w_hh_l1f = (const float*)d_in[10];
  const float* b_ih_l1f = (const float*)d_in[11];
  const float* b_hh_l1f = (const float*)d_in[12];
  const float* w_ih_l1b = (const float*)d_in[13];
  // d_in[14] = w_hh_l1b unused (reverse dir at t=T-1 has h=0)
  const float* b_ih_l1b = (const float*)d_in[15];
  const float* b_hh_l1b = (const float*)d_in[16];
  const float* fc_w     = (const float*)d_in[17];
  const float* fc_b     = (const float*)d_in[18];

  unsigned short* h0fT = (unsigned short*)d_ws;
  unsigned short* h0bT = h0fT + (size_t)Tt * Bsz * H;
  __half* xgT          = (__half*)(h0bT + (size_t)Tt * Bsz * H);
  unsigned short* pk0f = (unsigned short*)(xgT + (size_t)Tt * Bsz * G);
  unsigned short* pk0b = pk0f + 16 * NP * 8;
  unsigned short* pkhh = pk0b + 16 * NP * 8;
  unsigned short* pkxg = pkhh + 16 * NP * 8;
  unsigned short* pk1b = pkxg + 28 * NP * 8;

  pack_all<<<dim3(448, 5), 256, 0, stream>>>(
      w_hh_l0f, w_ih_l0f, b_ih_l0f, b_hh_l0f,
      w_hh_l0b, w_ih_l0b, b_ih_l0b, b_hh_l0b,
      w_hh_l1f, b_ih_l1f, b_hh_l1f,
      w_ih_l1f, w_ih_l1b, b_ih_l1b, b_hh_l1b,
      pk0f, pk0b, pkhh, pkxg, pk1b);

  lstm_l0<<<dim3(Bsz / MB, 2), 1024, 0, stream>>>(x, pk0f, pk0b, h0fT, h0bT);
  gemm_xg<<<(Bsz * Tt) / 64, 1024, 0, stream>>>(h0fT, h0bT, pkxg, xgT);
  lstm_l1<<<Bsz / MB, 1024, 0, stream>>>(h0fT, h0bT, pkhh, pk1b, xgT,
                                         fc_w, fc_b, (float*)d_out);
}